// Round 1
// baseline (11162.608 us; speedup 1.0000x reference)
//
#include <hip/hip_runtime.h>
#include <math.h>

// Problem constants (match reference)
#define D_DIM   1024
#define P_DIM   128
#define B_ROWS  4096
#define NS_ROWS 8192
#define NT_ROWS 8192
#define C_CLS   1000
#define EPS_BN  1e-5f
#define SCALE_S 0.1f
#define CHUNK   1024   // attention query-chunk rows

// GEMM tile config
#define TILE 64
#define BKK  16
#define PAD  4   // LDS row pad: keeps 16B alignment, breaks write conflicts

// Generic tiled fp32 GEMM: C[M,N] = epi(A[M,K] @ op(B) + bias)
//   BT=1: B is [N,K] (weight layout, uses B^T);  BT=0: B is [K,N]
// epi: 0=plain(+bias if non-null) 1=BN+ReLU 2=qkv interleaved scatter
//      3=+bias+addsrc (residual) 4=*exp(*ls_ptr)
__global__ __launch_bounds__(256)
void gemm_f32(const float* __restrict__ A, const float* __restrict__ B,
              float* __restrict__ C, int M, int N, int K, int BT, int epi,
              const float* __restrict__ bias,
              const float* __restrict__ bng, const float* __restrict__ bnb,
              const float* __restrict__ bnm, const float* __restrict__ bnv,
              float* __restrict__ q_out, float* __restrict__ k_out,
              float* __restrict__ v_out,
              const float* __restrict__ addsrc, const float* __restrict__ ls_ptr)
{
    __shared__ __align__(16) float As[BKK][TILE + PAD];
    __shared__ __align__(16) float Bs[BKK][TILE + PAD];

    const int tid = threadIdx.x;
    const int bm0 = blockIdx.y * TILE;
    const int bn0 = blockIdx.x * TILE;
    const int tx = tid & 15;       // -> 4 output cols
    const int ty = tid >> 4;       // -> 4 output rows
    const int la_m = tid >> 4;     // A/B(T) load: row-within-tile base
    const int la_k = tid & 15;     // A/B(T) load: k index
    const int lb_n = tid & 63;     // B (non-T) load
    const int lb_k = tid >> 6;

    float acc[4][4] = {};

    for (int k0 = 0; k0 < K; k0 += BKK) {
#pragma unroll
        for (int r = 0; r < 4; ++r) {
            int m = la_m + r * 16;
            int gm = bm0 + m;
            As[la_k][m] = (gm < M) ? A[(size_t)gm * K + k0 + la_k] : 0.f;
        }
        if (BT) {
#pragma unroll
            for (int r = 0; r < 4; ++r) {
                int n = la_m + r * 16;
                int gn = bn0 + n;
                Bs[la_k][n] = (gn < N) ? B[(size_t)gn * K + k0 + la_k] : 0.f;
            }
        } else {
#pragma unroll
            for (int r = 0; r < 4; ++r) {
                int k = lb_k + r * 4;
                int gn = bn0 + lb_n;
                Bs[k][lb_n] = (gn < N) ? B[(size_t)(k0 + k) * N + gn] : 0.f;
            }
        }
        __syncthreads();
#pragma unroll
        for (int k = 0; k < BKK; ++k) {
            float4 a4 = *(const float4*)&As[k][ty * 4];
            float4 b4 = *(const float4*)&Bs[k][tx * 4];
            float a[4] = {a4.x, a4.y, a4.z, a4.w};
            float b[4] = {b4.x, b4.y, b4.z, b4.w};
#pragma unroll
            for (int i = 0; i < 4; ++i)
#pragma unroll
                for (int j = 0; j < 4; ++j)
                    acc[i][j] = fmaf(a[i], b[j], acc[i][j]);
        }
        __syncthreads();
    }

    const float lsv = (epi == 4 && ls_ptr) ? expf(*ls_ptr) : 1.0f;

#pragma unroll
    for (int i = 0; i < 4; ++i) {
        int gm = bm0 + ty * 4 + i;
        if (gm >= M) continue;
#pragma unroll
        for (int j = 0; j < 4; ++j) {
            int gn = bn0 + tx * 4 + j;
            if (gn >= N) continue;
            float val = acc[i][j];
            if (bias) val += bias[gn];
            if (epi == 1) {
                val = (val - bnm[gn]) * rsqrtf(bnv[gn] + EPS_BN) * bng[gn] + bnb[gn];
                val = fmaxf(val, 0.f);
                C[(size_t)gm * N + gn] = val;
            } else if (epi == 2) {
                int d = gn / 3;
                int r = gn - 3 * d;   // gn % 3
                float* tgt = (r == 0) ? q_out : ((r == 1) ? k_out : v_out);
                if (tgt) tgt[(size_t)gm * D_DIM + d] = val;
            } else if (epi == 3) {
                C[(size_t)gm * N + gn] = val + addsrc[(size_t)gm * N + gn];
            } else if (epi == 4) {
                C[(size_t)gm * N + gn] = val * lsv;
            } else {
                C[(size_t)gm * N + gn] = val;
            }
        }
    }
}

// Row softmax over 8192 cols (applies SCALE_S first). One block per row.
__global__ __launch_bounds__(256)
void softmax_rows(float* __restrict__ S, int ncols)
{
    __shared__ float buf[NS_ROWS];   // 32 KiB
    __shared__ float red[8];
    const int tid = threadIdx.x;
    float* p = S + (size_t)blockIdx.x * ncols;

    float mx = -1e30f;
    for (int i = tid; i < ncols; i += 256) {
        float x = SCALE_S * p[i];
        buf[i] = x;
        mx = fmaxf(mx, x);
    }
    for (int o = 32; o > 0; o >>= 1) mx = fmaxf(mx, __shfl_down(mx, o, 64));
    if ((tid & 63) == 0) red[tid >> 6] = mx;
    __syncthreads();
    if (tid == 0) {
        float t = red[0];
        for (int w = 1; w < 4; ++w) t = fmaxf(t, red[w]);
        red[4] = t;
    }
    __syncthreads();
    mx = red[4];

    float sum = 0.f;
    for (int i = tid; i < ncols; i += 256) {
        float e = expf(buf[i] - mx);
        buf[i] = e;
        sum += e;
    }
    for (int o = 32; o > 0; o >>= 1) sum += __shfl_down(sum, o, 64);
    __syncthreads();
    if ((tid & 63) == 0) red[tid >> 6] = sum;
    __syncthreads();
    if (tid == 0) {
        float t = 0.f;
        for (int w = 0; w < 4; ++w) t += red[w];
        red[4] = t;
    }
    __syncthreads();
    const float inv = 1.0f / red[4];
    for (int i = tid; i < ncols; i += 256) p[i] = buf[i] * inv;
}

// Row L2-normalize G and write (or +=) into out. One block per row.
__global__ __launch_bounds__(256)
void rownorm_acc(const float* __restrict__ G, float* __restrict__ out,
                 int dcols, int accumulate)
{
    __shared__ float red[8];
    const int tid = threadIdx.x;
    const float* p = G + (size_t)blockIdx.x * dcols;
    float ss = 0.f;
    for (int i = tid; i < dcols; i += 256) {
        float v = p[i];
        ss = fmaf(v, v, ss);
    }
    for (int o = 32; o > 0; o >>= 1) ss += __shfl_down(ss, o, 64);
    if ((tid & 63) == 0) red[tid >> 6] = ss;
    __syncthreads();
    if (tid == 0) {
        float t = 0.f;
        for (int w = 0; w < 4; ++w) t += red[w];
        red[4] = t;
    }
    __syncthreads();
    const float inv = 1.0f / sqrtf(red[4]);
    float* o_ = out + (size_t)blockIdx.x * dcols;
    for (int i = tid; i < dcols; i += 256) {
        float v = p[i] * inv;
        if (accumulate) o_[i] += v;
        else            o_[i] = v;
    }
}

extern "C" void kernel_launch(void* const* d_in, const int* in_sizes, int n_in,
                              void* d_out, int out_size, void* d_ws, size_t ws_size,
                              hipStream_t stream)
{
    (void)in_sizes; (void)n_in; (void)out_size; (void)ws_size;

    const float* Ft  = (const float*)d_in[0];
    const float* Fv  = (const float*)d_in[1];
    const float* Fvs = (const float*)d_in[2];
    const float* Fvt = (const float*)d_in[3];
    const float* W1  = (const float*)d_in[4];
    const float* b1  = (const float*)d_in[5];
    const float* g1  = (const float*)d_in[6];
    const float* be1 = (const float*)d_in[7];
    const float* m1  = (const float*)d_in[8];
    const float* v1  = (const float*)d_in[9];
    const float* W2  = (const float*)d_in[10];
    const float* b2  = (const float*)d_in[11];
    const float* g2  = (const float*)d_in[12];
    const float* be2 = (const float*)d_in[13];
    const float* m2  = (const float*)d_in[14];
    const float* v2  = (const float*)d_in[15];
    const float* W3  = (const float*)d_in[16];
    const float* b3  = (const float*)d_in[17];
    const float* Wp  = (const float*)d_in[18];
    const float* bp  = (const float*)d_in[19];
    const float* ls  = (const float*)d_in[20];

    // Workspace layout (floats), with time-disjoint aliasing:
    //   q | k_s | v_s | k_t | v_t | Ys | Yt | G | Fsum
    //   h1,h2 alias Ys (pre-project phase only); Sbuf aliases G+Fsum.
    float* ws = (float*)d_ws;
    size_t off = 0;
    float* q    = ws + off; off += (size_t)B_ROWS * D_DIM;
    float* k_s  = ws + off; off += (size_t)NS_ROWS * D_DIM;
    float* v_s  = ws + off; off += (size_t)NS_ROWS * D_DIM;
    float* k_t  = ws + off; off += (size_t)NT_ROWS * D_DIM;
    float* v_t  = ws + off; off += (size_t)NT_ROWS * D_DIM;
    float* Ys   = ws + off; off += (size_t)B_ROWS * D_DIM;
    float* Yt   = ws + off; off += (size_t)B_ROWS * D_DIM;
    float* G    = ws + off; off += (size_t)B_ROWS * D_DIM;
    float* Fsum = ws + off; off += (size_t)B_ROWS * D_DIM;
    float* h1   = Ys;                              // [<=8192 x 128]
    float* h2   = Ys + (size_t)NS_ROWS * P_DIM;    // fits: 2*1M < 4.19M
    float* Sbuf = G;                               // [1024 x 8192] = G+Fsum

    auto gemm = [&](const float* A, const float* Bm, float* C, int M, int N,
                    int K, int BT, int epi, const float* bias,
                    const float* bg, const float* bb, const float* bm,
                    const float* bv, float* qo, float* ko, float* vo,
                    const float* addsrc, const float* lsp) {
        dim3 grid((N + TILE - 1) / TILE, (M + TILE - 1) / TILE);
        gemm_f32<<<grid, dim3(256), 0, stream>>>(
            A, Bm, C, M, N, K, BT, epi, bias, bg, bb, bm, bv, qo, ko, vo,
            addsrc, lsp);
    };

    // pre_project(Fv) -> q only
    gemm(Fv, W1, h1, B_ROWS, P_DIM, D_DIM, 1, 1, b1, g1, be1, m1, v1,
         nullptr, nullptr, nullptr, nullptr, nullptr);
    gemm(h1, W2, h2, B_ROWS, P_DIM, P_DIM, 1, 1, b2, g2, be2, m2, v2,
         nullptr, nullptr, nullptr, nullptr, nullptr);
    gemm(h2, W3, nullptr, B_ROWS, 3 * D_DIM, P_DIM, 1, 2, b3,
         nullptr, nullptr, nullptr, nullptr, q, nullptr, nullptr, nullptr, nullptr);

    // pre_project(Fvs_bank) -> k_s, v_s
    gemm(Fvs, W1, h1, NS_ROWS, P_DIM, D_DIM, 1, 1, b1, g1, be1, m1, v1,
         nullptr, nullptr, nullptr, nullptr, nullptr);
    gemm(h1, W2, h2, NS_ROWS, P_DIM, P_DIM, 1, 1, b2, g2, be2, m2, v2,
         nullptr, nullptr, nullptr, nullptr, nullptr);
    gemm(h2, W3, nullptr, NS_ROWS, 3 * D_DIM, P_DIM, 1, 2, b3,
         nullptr, nullptr, nullptr, nullptr, nullptr, k_s, v_s, nullptr, nullptr);

    // pre_project(Fvt_bank) -> k_t, v_t
    gemm(Fvt, W1, h1, NT_ROWS, P_DIM, D_DIM, 1, 1, b1, g1, be1, m1, v1,
         nullptr, nullptr, nullptr, nullptr, nullptr);
    gemm(h1, W2, h2, NT_ROWS, P_DIM, P_DIM, 1, 1, b2, g2, be2, m2, v2,
         nullptr, nullptr, nullptr, nullptr, nullptr);
    gemm(h2, W3, nullptr, NT_ROWS, 3 * D_DIM, P_DIM, 1, 2, b3,
         nullptr, nullptr, nullptr, nullptr, nullptr, k_t, v_t, nullptr, nullptr);

    // attention, both sides, in query chunks of CHUNK rows
    for (int side = 0; side < 2; ++side) {
        const float* kb = side ? k_t : k_s;
        const float* vb = side ? v_t : v_s;
        float* Y = side ? Yt : Ys;
        const int NK = side ? NT_ROWS : NS_ROWS;
        for (int c = 0; c < B_ROWS / CHUNK; ++c) {
            const float* qc = q + (size_t)c * CHUNK * D_DIM;
            gemm(qc, kb, Sbuf, CHUNK, NK, D_DIM, 1, 0,
                 nullptr, nullptr, nullptr, nullptr, nullptr,
                 nullptr, nullptr, nullptr, nullptr, nullptr);
            softmax_rows<<<dim3(CHUNK), dim3(256), 0, stream>>>(Sbuf, NK);
            gemm(Sbuf, vb, Y + (size_t)c * CHUNK * D_DIM, CHUNK, D_DIM, NK, 0, 0,
                 nullptr, nullptr, nullptr, nullptr, nullptr,
                 nullptr, nullptr, nullptr, nullptr, nullptr);
        }
    }

    // Fsa = Fv + Ys@Wp^T + bp ; Fsum = Fsa/||Fsa||  (then += for t side)
    gemm(Ys, Wp, G, B_ROWS, D_DIM, D_DIM, 1, 3, bp,
         nullptr, nullptr, nullptr, nullptr, nullptr, nullptr, nullptr, Fv, nullptr);
    rownorm_acc<<<dim3(B_ROWS), dim3(256), 0, stream>>>(G, Fsum, D_DIM, 0);
    gemm(Yt, Wp, G, B_ROWS, D_DIM, D_DIM, 1, 3, bp,
         nullptr, nullptr, nullptr, nullptr, nullptr, nullptr, nullptr, Fv, nullptr);
    rownorm_acc<<<dim3(B_ROWS), dim3(256), 0, stream>>>(G, Fsum, D_DIM, 1);

    // logits = exp(ls) * Fsum @ Ft^T   (BETA_S=BETA_T=1, shared Ft)
    gemm(Fsum, Ft, (float*)d_out, B_ROWS, C_CLS, D_DIM, 1, 4,
         nullptr, nullptr, nullptr, nullptr, nullptr,
         nullptr, nullptr, nullptr, nullptr, ls);
}

// Round 2
// 1474.035 us; speedup vs baseline: 7.5728x; 7.5728x over previous
//
#include <hip/hip_runtime.h>
#include <hip/hip_bf16.h>
#include <math.h>

#define D_DIM   1024
#define P_DIM   128
#define B_ROWS  4096
#define NBANK   8192
#define C_CLS   1000
#define EPS_BN  1e-5f
#define SCALE_S 0.1f
#define QCHUNK  1024   // attention S-chunk rows

typedef __bf16 bf16x8 __attribute__((ext_vector_type(8)));
typedef float  f32x4  __attribute__((ext_vector_type(4)));

// async global->LDS, 16B per lane; lds dest must be wave-uniform base (+lane*16 implicit)
__device__ __forceinline__ void load_lds16(const void* gp, void* lp) {
    __builtin_amdgcn_global_load_lds(
        (__attribute__((address_space(1))) void*)gp,
        (__attribute__((address_space(3))) void*)lp, 16, 0, 0);
}

// ---------------------------------------------------------------------------
// bf16 MFMA GEMM: C[M,N] = A[M,K] @ B[N,K]^T   (both row-major, bf16)
// M,N multiples of 128; K multiple of 32. 256 thr = 4 waves, each wave 64x64.
// epi: 0 fp32 store | 1 +bias,BN,ReLU -> bf16 | 2 qkv interleave scatter (bf16,
//      v transposed [D,vld]) | 3 +bias+addsrc -> fp32 | 4 *exp(*lsp) -> fp32
//      (cols < ldc only, row stride ldc) | 5 bf16 store
// ---------------------------------------------------------------------------
__global__ __launch_bounds__(256)
void gemm_bf16(const __hip_bfloat16* __restrict__ A,
               const __hip_bfloat16* __restrict__ B,
               int M, int N, int K, int epi,
               float* __restrict__ Cf, __hip_bfloat16* __restrict__ Cb,
               const float* __restrict__ bias,
               const float* __restrict__ bng, const float* __restrict__ bnb,
               const float* __restrict__ bnm, const float* __restrict__ bnv,
               __hip_bfloat16* __restrict__ qo, __hip_bfloat16* __restrict__ ko,
               __hip_bfloat16* __restrict__ vo, int vld,
               const float* __restrict__ addsrc, const float* __restrict__ lsp,
               int ldc)
{
    __shared__ __align__(16) short lsA[128 * 32];  // 8 KB, row-major [128][32]
    __shared__ __align__(16) short lsB[128 * 32];

    const int tid  = threadIdx.x;
    const int wave = tid >> 6;
    const int lane = tid & 63;
    const int wm   = wave >> 1;      // 2x2 wave grid over the 128x128 tile
    const int wn   = wave & 1;
    const int bm0  = blockIdx.y * 128;
    const int bn0  = blockIdx.x * 128;
    const int r16  = lane & 15;
    const int quad = lane >> 4;

    f32x4 acc[4][4];
#pragma unroll
    for (int i = 0; i < 4; ++i)
#pragma unroll
        for (int j = 0; j < 4; ++j) acc[i][j] = (f32x4){0.f, 0.f, 0.f, 0.f};

    for (int k0 = 0; k0 < K; k0 += 32) {
        // stage A,B tiles: 512 x 16B segments each; seg s -> row s>>2, cols (s&3)*8
#pragma unroll
        for (int i = 0; i < 2; ++i) {
            const int s   = i * 256 + tid;
            const int row = s >> 2;
            const int cc  = (s & 3) * 8;
            const int lofs = (i * 256 + wave * 64) * 16;  // wave-uniform
            load_lds16(A + (size_t)(bm0 + row) * K + k0 + cc, (char*)lsA + lofs);
            load_lds16(B + (size_t)(bn0 + row) * K + k0 + cc, (char*)lsB + lofs);
        }
        __syncthreads();

        bf16x8 af[4], bfr[4];
#pragma unroll
        for (int i = 0; i < 4; ++i)
            af[i] = *(const bf16x8*)(lsA + (wm * 64 + i * 16 + r16) * 32 + quad * 8);
#pragma unroll
        for (int j = 0; j < 4; ++j)
            bfr[j] = *(const bf16x8*)(lsB + (wn * 64 + j * 16 + r16) * 32 + quad * 8);
#pragma unroll
        for (int i = 0; i < 4; ++i)
#pragma unroll
            for (int j = 0; j < 4; ++j)
                acc[i][j] = __builtin_amdgcn_mfma_f32_16x16x32_bf16(
                    af[i], bfr[j], acc[i][j], 0, 0, 0);
        __syncthreads();
    }

    const float lsv = (epi == 4) ? expf(*lsp) : 1.0f;

    // C/D layout: col = lane&15, row = quad*4 + reg  [m89/m91 verified]
#pragma unroll
    for (int i = 0; i < 4; ++i) {
        const int gmb = bm0 + wm * 64 + i * 16 + quad * 4;
#pragma unroll
        for (int j = 0; j < 4; ++j) {
            const int gn = bn0 + wn * 64 + j * 16 + r16;
#pragma unroll
            for (int r = 0; r < 4; ++r) {
                const int gm = gmb + r;
                float val = acc[i][j][r];
                if (epi == 0) {
                    Cf[(size_t)gm * N + gn] = val;
                } else if (epi == 1) {
                    float x = val + bias[gn];
                    x = (x - bnm[gn]) * rsqrtf(bnv[gn] + EPS_BN) * bng[gn] + bnb[gn];
                    Cb[(size_t)gm * N + gn] = __float2bfloat16(fmaxf(x, 0.f));
                } else if (epi == 2) {
                    float x = val + bias[gn];
                    int d = gn / 3, rr = gn - 3 * d;
                    if (rr == 0)      { if (qo) qo[(size_t)gm * D_DIM + d] = __float2bfloat16(x); }
                    else if (rr == 1) { if (ko) ko[(size_t)gm * D_DIM + d] = __float2bfloat16(x); }
                    else              { if (vo) vo[(size_t)d * vld + gm]   = __float2bfloat16(x); }
                } else if (epi == 3) {
                    Cf[(size_t)gm * N + gn] = val + bias[gn] + addsrc[(size_t)gm * N + gn];
                } else if (epi == 4) {
                    if (gn < ldc) Cf[(size_t)gm * ldc + gn] = val * lsv;
                } else {
                    Cb[(size_t)gm * N + gn] = __float2bfloat16(val);
                }
            }
        }
    }
}

// row softmax over 8192 cols of fp32 S (applies SCALE_S), writes bf16 A
__global__ __launch_bounds__(256)
void softmax_bf16(const float* __restrict__ S, __hip_bfloat16* __restrict__ Aout,
                  int ncols)
{
    __shared__ float buf[NBANK];   // 32 KB
    __shared__ float red[8];
    const int tid = threadIdx.x;
    const float* p = S + (size_t)blockIdx.x * ncols;
    __hip_bfloat16* o = Aout + (size_t)blockIdx.x * ncols;

    float mx = -1e30f;
    for (int i = tid; i < ncols; i += 256) {
        float x = SCALE_S * p[i];
        buf[i] = x;
        mx = fmaxf(mx, x);
    }
    for (int s = 32; s > 0; s >>= 1) mx = fmaxf(mx, __shfl_down(mx, s, 64));
    if ((tid & 63) == 0) red[tid >> 6] = mx;
    __syncthreads();
    if (tid == 0) {
        float t = red[0];
        for (int w = 1; w < 4; ++w) t = fmaxf(t, red[w]);
        red[4] = t;
    }
    __syncthreads();
    mx = red[4];

    float sum = 0.f;
    for (int i = tid; i < ncols; i += 256) {
        float e = expf(buf[i] - mx);
        buf[i] = e;
        sum += e;
    }
    for (int s = 32; s > 0; s >>= 1) sum += __shfl_down(sum, s, 64);
    __syncthreads();
    if ((tid & 63) == 0) red[tid >> 6] = sum;
    __syncthreads();
    if (tid == 0) {
        float t = 0.f;
        for (int w = 0; w < 4; ++w) t += red[w];
        red[5] = t;
    }
    __syncthreads();
    const float inv = 1.0f / red[5];
    for (int i = tid; i < ncols; i += 256) o[i] = __float2bfloat16(buf[i] * inv);
}

// row L2-normalize G (fp32) into out (write or +=)
__global__ __launch_bounds__(256)
void rownorm_acc(const float* __restrict__ G, float* __restrict__ out,
                 int dcols, int accumulate)
{
    __shared__ float red[8];
    const int tid = threadIdx.x;
    const float* p = G + (size_t)blockIdx.x * dcols;
    float ss = 0.f;
    for (int i = tid; i < dcols; i += 256) { float v = p[i]; ss = fmaf(v, v, ss); }
    for (int s = 32; s > 0; s >>= 1) ss += __shfl_down(ss, s, 64);
    if ((tid & 63) == 0) red[tid >> 6] = ss;
    __syncthreads();
    if (tid == 0) {
        float t = 0.f;
        for (int w = 0; w < 4; ++w) t += red[w];
        red[4] = t;
    }
    __syncthreads();
    const float inv = 1.0f / sqrtf(red[4]);
    float* o_ = out + (size_t)blockIdx.x * dcols;
    for (int i = tid; i < dcols; i += 256) {
        float v = p[i] * inv;
        if (accumulate) o_[i] += v; else o_[i] = v;
    }
}

// fp32 -> bf16 elementwise, 8/thread
__global__ __launch_bounds__(256)
void f2b(const float* __restrict__ in, __hip_bfloat16* __restrict__ out, int n)
{
    int i = (blockIdx.x * 256 + threadIdx.x) * 8;
    if (i + 8 > n) return;
    float4 a = *(const float4*)(in + i);
    float4 b = *(const float4*)(in + i + 4);
    union { __hip_bfloat16 h[8]; int4 v; } u;
    u.h[0] = __float2bfloat16(a.x); u.h[1] = __float2bfloat16(a.y);
    u.h[2] = __float2bfloat16(a.z); u.h[3] = __float2bfloat16(a.w);
    u.h[4] = __float2bfloat16(b.x); u.h[5] = __float2bfloat16(b.y);
    u.h[6] = __float2bfloat16(b.z); u.h[7] = __float2bfloat16(b.w);
    *(int4*)(out + i) = u.v;
}

// Ft [1000,1024] fp32 -> [1024,1024] bf16, rows 1000..1023 zero
__global__ __launch_bounds__(256)
void ftpad(const float* __restrict__ Ft, __hip_bfloat16* __restrict__ out)
{
    int idx = blockIdx.x * 256 + threadIdx.x;
    int row = idx >> 10, col = idx & 1023;
    float v = (row < C_CLS) ? Ft[(size_t)row * D_DIM + col] : 0.f;
    out[idx] = __float2bfloat16(v);
}

extern "C" void kernel_launch(void* const* d_in, const int* in_sizes, int n_in,
                              void* d_out, int out_size, void* d_ws, size_t ws_size,
                              hipStream_t stream)
{
    (void)in_sizes; (void)n_in; (void)out_size; (void)ws_size;

    const float* Ft  = (const float*)d_in[0];
    const float* Fv  = (const float*)d_in[1];
    const float* Fvs = (const float*)d_in[2];
    const float* Fvt = (const float*)d_in[3];
    const float* W1  = (const float*)d_in[4];
    const float* b1  = (const float*)d_in[5];
    const float* g1  = (const float*)d_in[6];
    const float* be1 = (const float*)d_in[7];
    const float* m1  = (const float*)d_in[8];
    const float* v1  = (const float*)d_in[9];
    const float* W2  = (const float*)d_in[10];
    const float* b2  = (const float*)d_in[11];
    const float* g2  = (const float*)d_in[12];
    const float* be2 = (const float*)d_in[13];
    const float* m2  = (const float*)d_in[14];
    const float* v2  = (const float*)d_in[15];
    const float* W3  = (const float*)d_in[16];
    const float* b3  = (const float*)d_in[17];
    const float* Wp  = (const float*)d_in[18];
    const float* bp  = (const float*)d_in[19];
    const float* ls  = (const float*)d_in[20];

    // ---- workspace layout (bytes), phase-disjoint aliasing ----
    char* base = (char*)d_ws;
    size_t o = 0;
    auto take = [&](size_t s) { size_t r = o; o += (s + 255) & ~(size_t)255; return r; };
    typedef __hip_bfloat16 bf;

    bf* qb   = (bf*)(base + take((size_t)B_ROWS * D_DIM * 2));   // persistent P2->P3
    bf* ksb  = (bf*)(base + take((size_t)NBANK * D_DIM * 2));
    bf* ktb  = (bf*)(base + take((size_t)NBANK * D_DIM * 2));
    bf* vsT  = (bf*)(base + take((size_t)D_DIM * NBANK * 2));    // [D, NBANK]
    bf* vtT  = (bf*)(base + take((size_t)D_DIM * NBANK * 2));
    bf* Ysb  = (bf*)(base + take((size_t)B_ROWS * D_DIM * 2));   // P3->P4
    bf* Ytb  = (bf*)(base + take((size_t)B_ROWS * D_DIM * 2));
    bf* Wpb  = (bf*)(base + take((size_t)D_DIM * D_DIM * 2));    // P1->P4
    bf* Ftb  = (bf*)(base + take((size_t)D_DIM * D_DIM * 2));    // padded to 1024 rows
    size_t Dbase = o;
    // region D, phase P3: S chunk (fp32) + full A (bf16)
    float* S  = (float*)(base + Dbase);
    bf*    Ab = (bf*)(base + Dbase + ((size_t)QCHUNK * NBANK * 4 + 255 & ~(size_t)255));
    // region D, phase P2 (same memory, earlier in time)
    size_t p = Dbase;
    auto take2 = [&](size_t s) { size_t r = p; p += (s + 255) & ~(size_t)255; return r; };
    bf* Fvb  = (bf*)(base + take2((size_t)B_ROWS * D_DIM * 2));
    bf* Fvsb = (bf*)(base + take2((size_t)NBANK * D_DIM * 2));
    bf* Fvtb = (bf*)(base + take2((size_t)NBANK * D_DIM * 2));
    bf* W1b  = (bf*)(base + take2((size_t)P_DIM * D_DIM * 2));
    bf* W2b  = (bf*)(base + take2((size_t)P_DIM * P_DIM * 2));
    bf* W3b  = (bf*)(base + take2((size_t)3 * D_DIM * P_DIM * 2));
    bf* h1b  = (bf*)(base + take2((size_t)NBANK * P_DIM * 2));
    bf* h2b  = (bf*)(base + take2((size_t)NBANK * P_DIM * 2));
    // phase P4 aliases the (dead) qkv region at offset 0
    float* G     = (float*)(base + 0);
    float* Fsum  = (float*)(base + (size_t)B_ROWS * D_DIM * 4);
    bf*    Fsumb = (bf*)(base + (size_t)B_ROWS * D_DIM * 8);

    auto gemm = [&](const bf* A, const bf* B, int M, int N, int K, int epi,
                    float* Cf, bf* Cb, const float* bias,
                    const float* bg, const float* bb, const float* bm, const float* bv,
                    bf* qo, bf* ko, bf* vo, int vld,
                    const float* addsrc, const float* lsp, int ldc) {
        gemm_bf16<<<dim3(N / 128, M / 128), dim3(256), 0, stream>>>(
            A, B, M, N, K, epi, Cf, Cb, bias, bg, bb, bm, bv,
            qo, ko, vo, vld, addsrc, lsp, ldc);
    };
    auto conv = [&](const float* in, bf* out, size_t n) {
        f2b<<<dim3((unsigned)((n / 8 + 255) / 256)), dim3(256), 0, stream>>>(in, out, (int)n);
    };

    // P1: dtype conversions
    conv(Fv,  Fvb,  (size_t)B_ROWS * D_DIM);
    conv(Fvs, Fvsb, (size_t)NBANK * D_DIM);
    conv(Fvt, Fvtb, (size_t)NBANK * D_DIM);
    conv(W1,  W1b,  (size_t)P_DIM * D_DIM);
    conv(W2,  W2b,  (size_t)P_DIM * P_DIM);
    conv(W3,  W3b,  (size_t)3 * D_DIM * P_DIM);
    conv(Wp,  Wpb,  (size_t)D_DIM * D_DIM);
    ftpad<<<dim3(D_DIM * D_DIM / 256), dim3(256), 0, stream>>>(Ft, Ftb);

    // P2: pre_project for Fv (q only), Fvs (k,v), Fvt (k,v)
    struct { const bf* x; int M; bf *q, *k, *v; } pre[3] = {
        {Fvb,  B_ROWS, qb,      nullptr, nullptr},
        {Fvsb, NBANK,  nullptr, ksb,     vsT},
        {Fvtb, NBANK,  nullptr, ktb,     vtT},
    };
    for (int t = 0; t < 3; ++t) {
        gemm(pre[t].x, W1b, pre[t].M, P_DIM, D_DIM, 1, nullptr, h1b,
             b1, g1, be1, m1, v1, nullptr, nullptr, nullptr, 0, nullptr, nullptr, 0);
        gemm(h1b, W2b, pre[t].M, P_DIM, P_DIM, 1, nullptr, h2b,
             b2, g2, be2, m2, v2, nullptr, nullptr, nullptr, 0, nullptr, nullptr, 0);
        gemm(h2b, W3b, pre[t].M, 3 * D_DIM, P_DIM, 2, nullptr, nullptr,
             b3, nullptr, nullptr, nullptr, nullptr,
             pre[t].q, pre[t].k, pre[t].v, pre[t].M, nullptr, nullptr, 0);
    }

    // P3: attention, both sides
    for (int side = 0; side < 2; ++side) {
        const bf* kb = side ? ktb : ksb;
        const bf* vT = side ? vtT : vsT;
        bf* Yb = side ? Ytb : Ysb;
        for (int c = 0; c < B_ROWS / QCHUNK; ++c) {
            gemm(qb + (size_t)c * QCHUNK * D_DIM, kb, QCHUNK, NBANK, D_DIM, 0,
                 S, nullptr, nullptr, nullptr, nullptr, nullptr, nullptr,
                 nullptr, nullptr, nullptr, 0, nullptr, nullptr, 0);
            softmax_bf16<<<dim3(QCHUNK), dim3(256), 0, stream>>>(
                S, Ab + (size_t)c * QCHUNK * NBANK, NBANK);
        }
        gemm(Ab, vT, B_ROWS, D_DIM, NBANK, 5, nullptr, Yb,
             nullptr, nullptr, nullptr, nullptr, nullptr,
             nullptr, nullptr, nullptr, 0, nullptr, nullptr, 0);
    }

    // P4: post-project + residual + rownorm + logits
    gemm(Ysb, Wpb, B_ROWS, D_DIM, D_DIM, 3, G, nullptr, bp,
         nullptr, nullptr, nullptr, nullptr, nullptr, nullptr, nullptr, 0, Fv, nullptr, 0);
    rownorm_acc<<<dim3(B_ROWS), dim3(256), 0, stream>>>(G, Fsum, D_DIM, 0);
    gemm(Ytb, Wpb, B_ROWS, D_DIM, D_DIM, 3, G, nullptr, bp,
         nullptr, nullptr, nullptr, nullptr, nullptr, nullptr, nullptr, 0, Fv, nullptr, 0);
    rownorm_acc<<<dim3(B_ROWS), dim3(256), 0, stream>>>(G, Fsum, D_DIM, 1);
    conv(Fsum, Fsumb, (size_t)B_ROWS * D_DIM);
    gemm(Fsumb, Ftb, B_ROWS, D_DIM, D_DIM, 4, (float*)d_out, nullptr,
         nullptr, nullptr, nullptr, nullptr, nullptr,
         nullptr, nullptr, nullptr, 0, nullptr, ls, C_CLS);
}

// Round 3
// 1434.824 us; speedup vs baseline: 7.7798x; 1.0273x over previous
//
#include <hip/hip_runtime.h>
#include <hip/hip_bf16.h>
#include <math.h>

#define D_DIM   1024
#define P_DIM   128
#define B_ROWS  4096
#define NBANK   8192
#define C_CLS   1000
#define EPS_BN  1e-5f
#define SCALE_S 0.1f

typedef __bf16 bf16x8 __attribute__((ext_vector_type(8)));
typedef float  f32x4  __attribute__((ext_vector_type(4)));

// async global->LDS, 16B per lane; lds dest must be wave-uniform base (+lane*16 implicit)
__device__ __forceinline__ void load_lds16(const void* gp, void* lp) {
    __builtin_amdgcn_global_load_lds(
        (__attribute__((address_space(1))) void*)gp,
        (__attribute__((address_space(3))) void*)lp, 16, 0, 0);
}

// ---------------------------------------------------------------------------
// bf16 MFMA GEMM: C[M,N] = A[M,K] @ B[N,K]^T   (both row-major, bf16)
// M,N multiples of 128; K multiple of 32. 256 thr = 4 waves, each wave 64x64.
// epi: 0 fp32 store | 1 +bias,BN,ReLU -> bf16 | 2 qkv interleave scatter (bf16,
//      v transposed [D,vld]) | 3 +bias+addsrc -> fp32 | 4 *exp(*lsp) -> fp32
//      (cols < ldc only, row stride ldc) | 5 bf16 store
// ---------------------------------------------------------------------------
__global__ __launch_bounds__(256)
void gemm_bf16(const __hip_bfloat16* __restrict__ A,
               const __hip_bfloat16* __restrict__ B,
               int M, int N, int K, int epi,
               float* __restrict__ Cf, __hip_bfloat16* __restrict__ Cb,
               const float* __restrict__ bias,
               const float* __restrict__ bng, const float* __restrict__ bnb,
               const float* __restrict__ bnm, const float* __restrict__ bnv,
               __hip_bfloat16* __restrict__ qo, __hip_bfloat16* __restrict__ ko,
               __hip_bfloat16* __restrict__ vo, int vld,
               const float* __restrict__ addsrc, const float* __restrict__ lsp,
               int ldc)
{
    __shared__ __align__(16) short lsA[128 * 32];  // 8 KB, row-major [128][32]
    __shared__ __align__(16) short lsB[128 * 32];

    const int tid  = threadIdx.x;
    const int wave = tid >> 6;
    const int lane = tid & 63;
    const int wm   = wave >> 1;      // 2x2 wave grid over the 128x128 tile
    const int wn   = wave & 1;
    const int bm0  = blockIdx.y * 128;
    const int bn0  = blockIdx.x * 128;
    const int r16  = lane & 15;
    const int quad = lane >> 4;

    f32x4 acc[4][4];
#pragma unroll
    for (int i = 0; i < 4; ++i)
#pragma unroll
        for (int j = 0; j < 4; ++j) acc[i][j] = (f32x4){0.f, 0.f, 0.f, 0.f};

    for (int k0 = 0; k0 < K; k0 += 32) {
        // stage A,B tiles: 512 x 16B segments each; seg s -> row s>>2, cols (s&3)*8
#pragma unroll
        for (int i = 0; i < 2; ++i) {
            const int s   = i * 256 + tid;
            const int row = s >> 2;
            const int cc  = (s & 3) * 8;
            const int lofs = (i * 256 + wave * 64) * 16;  // wave-uniform
            load_lds16(A + (size_t)(bm0 + row) * K + k0 + cc, (char*)lsA + lofs);
            load_lds16(B + (size_t)(bn0 + row) * K + k0 + cc, (char*)lsB + lofs);
        }
        __syncthreads();

        bf16x8 af[4], bfr[4];
#pragma unroll
        for (int i = 0; i < 4; ++i)
            af[i] = *(const bf16x8*)(lsA + (wm * 64 + i * 16 + r16) * 32 + quad * 8);
#pragma unroll
        for (int j = 0; j < 4; ++j)
            bfr[j] = *(const bf16x8*)(lsB + (wn * 64 + j * 16 + r16) * 32 + quad * 8);
#pragma unroll
        for (int i = 0; i < 4; ++i)
#pragma unroll
            for (int j = 0; j < 4; ++j)
                acc[i][j] = __builtin_amdgcn_mfma_f32_16x16x32_bf16(
                    af[i], bfr[j], acc[i][j], 0, 0, 0);
        __syncthreads();
    }

    const float lsv = (epi == 4) ? expf(*lsp) : 1.0f;

    // C/D layout: col = lane&15, row = quad*4 + reg  [m89/m91 verified]
#pragma unroll
    for (int i = 0; i < 4; ++i) {
        const int gmb = bm0 + wm * 64 + i * 16 + quad * 4;
#pragma unroll
        for (int j = 0; j < 4; ++j) {
            const int gn = bn0 + wn * 64 + j * 16 + r16;
#pragma unroll
            for (int r = 0; r < 4; ++r) {
                const int gm = gmb + r;
                float val = acc[i][j][r];
                if (epi == 0) {
                    Cf[(size_t)gm * N + gn] = val;
                } else if (epi == 1) {
                    float x = val + bias[gn];
                    x = (x - bnm[gn]) * rsqrtf(bnv[gn] + EPS_BN) * bng[gn] + bnb[gn];
                    Cb[(size_t)gm * N + gn] = __float2bfloat16(fmaxf(x, 0.f));
                } else if (epi == 2) {
                    float x = val + bias[gn];
                    int d = gn / 3, rr = gn - 3 * d;
                    if (rr == 0)      { if (qo) qo[(size_t)gm * D_DIM + d] = __float2bfloat16(x); }
                    else if (rr == 1) { if (ko) ko[(size_t)gm * D_DIM + d] = __float2bfloat16(x); }
                    else              { if (vo) vo[(size_t)d * vld + gm]   = __float2bfloat16(x); }
                } else if (epi == 3) {
                    Cf[(size_t)gm * N + gn] = val + bias[gn] + addsrc[(size_t)gm * N + gn];
                } else if (epi == 4) {
                    if (gn < ldc) Cf[(size_t)gm * ldc + gn] = val * lsv;
                } else {
                    Cb[(size_t)gm * N + gn] = __float2bfloat16(val);
                }
            }
        }
    }
}

// in-place row softmax over ncols bf16 (applies SCALE_S), one block per row
__global__ __launch_bounds__(256)
void softmax_bf16(__hip_bfloat16* __restrict__ S, int ncols)
{
    __shared__ float buf[NBANK];   // 32 KB
    __shared__ float red[8];
    const int tid = threadIdx.x;
    __hip_bfloat16* p = S + (size_t)blockIdx.x * ncols;

    float mx = -1e30f;
    for (int i = tid; i < ncols; i += 256) {
        float x = SCALE_S * __bfloat162float(p[i]);
        buf[i] = x;
        mx = fmaxf(mx, x);
    }
    for (int s = 32; s > 0; s >>= 1) mx = fmaxf(mx, __shfl_down(mx, s, 64));
    if ((tid & 63) == 0) red[tid >> 6] = mx;
    __syncthreads();
    if (tid == 0) {
        float t = red[0];
        for (int w = 1; w < 4; ++w) t = fmaxf(t, red[w]);
        red[4] = t;
    }
    __syncthreads();
    mx = red[4];

    float sum = 0.f;
    for (int i = tid; i < ncols; i += 256) {
        float e = expf(buf[i] - mx);
        buf[i] = e;
        sum += e;
    }
    for (int s = 32; s > 0; s >>= 1) sum += __shfl_down(sum, s, 64);
    __syncthreads();
    if ((tid & 63) == 0) red[tid >> 6] = sum;
    __syncthreads();
    if (tid == 0) {
        float t = 0.f;
        for (int w = 0; w < 4; ++w) t += red[w];
        red[5] = t;
    }
    __syncthreads();
    const float inv = 1.0f / red[5];
    for (int i = tid; i < ncols; i += 256) p[i] = __float2bfloat16(buf[i] * inv);
}

// row L2-normalize G (fp32) into out (write or +=)
__global__ __launch_bounds__(256)
void rownorm_acc(const float* __restrict__ G, float* __restrict__ out,
                 int dcols, int accumulate)
{
    __shared__ float red[8];
    const int tid = threadIdx.x;
    const float* p = G + (size_t)blockIdx.x * dcols;
    float ss = 0.f;
    for (int i = tid; i < dcols; i += 256) { float v = p[i]; ss = fmaf(v, v, ss); }
    for (int s = 32; s > 0; s >>= 1) ss += __shfl_down(ss, s, 64);
    if ((tid & 63) == 0) red[tid >> 6] = ss;
    __syncthreads();
    if (tid == 0) {
        float t = 0.f;
        for (int w = 0; w < 4; ++w) t += red[w];
        red[4] = t;
    }
    __syncthreads();
    const float inv = 1.0f / sqrtf(red[4]);
    float* o_ = out + (size_t)blockIdx.x * dcols;
    for (int i = tid; i < dcols; i += 256) {
        float v = p[i] * inv;
        if (accumulate) o_[i] += v; else o_[i] = v;
    }
}

// fp32 -> bf16 elementwise, 8/thread
__global__ __launch_bounds__(256)
void f2b(const float* __restrict__ in, __hip_bfloat16* __restrict__ out, int n)
{
    int i = (blockIdx.x * 256 + threadIdx.x) * 8;
    if (i + 8 > n) return;
    float4 a = *(const float4*)(in + i);
    float4 b = *(const float4*)(in + i + 4);
    union { __hip_bfloat16 h[8]; int4 v; } u;
    u.h[0] = __float2bfloat16(a.x); u.h[1] = __float2bfloat16(a.y);
    u.h[2] = __float2bfloat16(a.z); u.h[3] = __float2bfloat16(a.w);
    u.h[4] = __float2bfloat16(b.x); u.h[5] = __float2bfloat16(b.y);
    u.h[6] = __float2bfloat16(b.z); u.h[7] = __float2bfloat16(b.w);
    *(int4*)(out + i) = u.v;
}

// Ft [1000,1024] fp32 -> [1024,1024] bf16, rows 1000..1023 zero
__global__ __launch_bounds__(256)
void ftpad(const float* __restrict__ Ft, __hip_bfloat16* __restrict__ out)
{
    int idx = blockIdx.x * 256 + threadIdx.x;
    int row = idx >> 10, col = idx & 1023;
    float v = (row < C_CLS) ? Ft[(size_t)row * D_DIM + col] : 0.f;
    out[idx] = __float2bfloat16(v);
}

extern "C" void kernel_launch(void* const* d_in, const int* in_sizes, int n_in,
                              void* d_out, int out_size, void* d_ws, size_t ws_size,
                              hipStream_t stream)
{
    (void)in_sizes; (void)n_in; (void)out_size; (void)ws_size;

    const float* Ft  = (const float*)d_in[0];
    const float* Fv  = (const float*)d_in[1];
    const float* Fvs = (const float*)d_in[2];
    const float* Fvt = (const float*)d_in[3];
    const float* W1  = (const float*)d_in[4];
    const float* b1  = (const float*)d_in[5];
    const float* g1  = (const float*)d_in[6];
    const float* be1 = (const float*)d_in[7];
    const float* m1  = (const float*)d_in[8];
    const float* v1  = (const float*)d_in[9];
    const float* W2  = (const float*)d_in[10];
    const float* b2  = (const float*)d_in[11];
    const float* g2  = (const float*)d_in[12];
    const float* be2 = (const float*)d_in[13];
    const float* m2  = (const float*)d_in[14];
    const float* v2  = (const float*)d_in[15];
    const float* W3  = (const float*)d_in[16];
    const float* b3  = (const float*)d_in[17];
    const float* Wp  = (const float*)d_in[18];
    const float* bp  = (const float*)d_in[19];
    const float* ls  = (const float*)d_in[20];

    // ---- workspace layout (bytes), phase-disjoint aliasing ----
    char* base = (char*)d_ws;
    size_t o = 0;
    auto take = [&](size_t s) { size_t r = o; o += (s + 255) & ~(size_t)255; return r; };
    typedef __hip_bfloat16 bf;

    // persistent across phases (~92 MB)
    bf* qb   = (bf*)(base + take((size_t)B_ROWS * D_DIM * 2));   // P2->P3
    bf* ksb  = (bf*)(base + take((size_t)NBANK * D_DIM * 2));
    bf* ktb  = (bf*)(base + take((size_t)NBANK * D_DIM * 2));
    bf* vsT  = (bf*)(base + take((size_t)D_DIM * NBANK * 2));    // [D, NBANK]
    bf* vtT  = (bf*)(base + take((size_t)D_DIM * NBANK * 2));
    bf* Ysb  = (bf*)(base + take((size_t)B_ROWS * D_DIM * 2));   // P3->P4
    bf* Ytb  = (bf*)(base + take((size_t)B_ROWS * D_DIM * 2));
    bf* Wpb  = (bf*)(base + take((size_t)D_DIM * D_DIM * 2));    // P1->P4
    bf* Ftb  = (bf*)(base + take((size_t)D_DIM * D_DIM * 2));
    // region D (64 MB): P3 holds full bf16 S/A; P2 and P4 alias into it.
    size_t Dbase = o;
    bf* Sb = (bf*)(base + Dbase);                                // [4096, 8192] bf16
    size_t p = Dbase;
    auto take2 = [&](size_t s) { size_t r = p; p += (s + 255) & ~(size_t)255; return r; };
    bf* Fvb  = (bf*)(base + take2((size_t)B_ROWS * D_DIM * 2));
    bf* Fvsb = (bf*)(base + take2((size_t)NBANK * D_DIM * 2));
    bf* Fvtb = (bf*)(base + take2((size_t)NBANK * D_DIM * 2));
    bf* W1b  = (bf*)(base + take2((size_t)P_DIM * D_DIM * 2));
    bf* W2b  = (bf*)(base + take2((size_t)P_DIM * P_DIM * 2));
    bf* W3b  = (bf*)(base + take2((size_t)3 * D_DIM * P_DIM * 2));
    bf* h1b  = (bf*)(base + take2((size_t)NBANK * P_DIM * 2));
    bf* h2b  = (bf*)(base + take2((size_t)NBANK * P_DIM * 2));
    // P4 aliases region D (S dead by then)
    float* G     = (float*)(base + Dbase);
    float* Fsum  = (float*)(base + Dbase + (size_t)B_ROWS * D_DIM * 4);
    bf*    Fsumb = (bf*)(base + Dbase + (size_t)B_ROWS * D_DIM * 8);

    auto gemm = [&](const bf* A, const bf* B, int M, int N, int K, int epi,
                    float* Cf, bf* Cb, const float* bias,
                    const float* bg, const float* bb, const float* bm, const float* bv,
                    bf* qo, bf* ko, bf* vo, int vld,
                    const float* addsrc, const float* lsp, int ldc) {
        gemm_bf16<<<dim3(N / 128, M / 128), dim3(256), 0, stream>>>(
            A, B, M, N, K, epi, Cf, Cb, bias, bg, bb, bm, bv,
            qo, ko, vo, vld, addsrc, lsp, ldc);
    };
    auto conv = [&](const float* in, bf* out, size_t n) {
        f2b<<<dim3((unsigned)((n / 8 + 255) / 256)), dim3(256), 0, stream>>>(in, out, (int)n);
    };

    // P1: dtype conversions
    conv(Fv,  Fvb,  (size_t)B_ROWS * D_DIM);
    conv(Fvs, Fvsb, (size_t)NBANK * D_DIM);
    conv(Fvt, Fvtb, (size_t)NBANK * D_DIM);
    conv(W1,  W1b,  (size_t)P_DIM * D_DIM);
    conv(W2,  W2b,  (size_t)P_DIM * P_DIM);
    conv(W3,  W3b,  (size_t)3 * D_DIM * P_DIM);
    conv(Wp,  Wpb,  (size_t)D_DIM * D_DIM);
    ftpad<<<dim3(D_DIM * D_DIM / 256), dim3(256), 0, stream>>>(Ft, Ftb);

    // P2: pre_project for Fv (q only), Fvs (k,v), Fvt (k,v)
    struct { const bf* x; int M; bf *q, *k, *v; } pre[3] = {
        {Fvb,  B_ROWS, qb,      nullptr, nullptr},
        {Fvsb, NBANK,  nullptr, ksb,     vsT},
        {Fvtb, NBANK,  nullptr, ktb,     vtT},
    };
    for (int t = 0; t < 3; ++t) {
        gemm(pre[t].x, W1b, pre[t].M, P_DIM, D_DIM, 1, nullptr, h1b,
             b1, g1, be1, m1, v1, nullptr, nullptr, nullptr, 0, nullptr, nullptr, 0);
        gemm(h1b, W2b, pre[t].M, P_DIM, P_DIM, 1, nullptr, h2b,
             b2, g2, be2, m2, v2, nullptr, nullptr, nullptr, 0, nullptr, nullptr, 0);
        gemm(h2b, W3b, pre[t].M, 3 * D_DIM, P_DIM, 2, nullptr, nullptr,
             b3, nullptr, nullptr, nullptr, nullptr,
             pre[t].q, pre[t].k, pre[t].v, pre[t].M, nullptr, nullptr, 0);
    }

    // P3: attention, both sides — full-size QK^T (bf16 S), in-place softmax, A@V
    for (int side = 0; side < 2; ++side) {
        const bf* kb = side ? ktb : ksb;
        const bf* vT = side ? vtT : vsT;
        bf* Yb = side ? Ytb : Ysb;
        gemm(qb, kb, B_ROWS, NBANK, D_DIM, 5, nullptr, Sb,
             nullptr, nullptr, nullptr, nullptr, nullptr,
             nullptr, nullptr, nullptr, 0, nullptr, nullptr, 0);
        softmax_bf16<<<dim3(B_ROWS), dim3(256), 0, stream>>>(Sb, NBANK);
        gemm(Sb, vT, B_ROWS, D_DIM, NBANK, 5, nullptr, Yb,
             nullptr, nullptr, nullptr, nullptr, nullptr,
             nullptr, nullptr, nullptr, 0, nullptr, nullptr, 0);
    }

    // P4: post-project + residual + rownorm + logits
    gemm(Ysb, Wpb, B_ROWS, D_DIM, D_DIM, 3, G, nullptr, bp,
         nullptr, nullptr, nullptr, nullptr, nullptr, nullptr, nullptr, 0, Fv, nullptr, 0);
    rownorm_acc<<<dim3(B_ROWS), dim3(256), 0, stream>>>(G, Fsum, D_DIM, 0);
    gemm(Ytb, Wpb, B_ROWS, D_DIM, D_DIM, 3, G, nullptr, bp,
         nullptr, nullptr, nullptr, nullptr, nullptr, nullptr, nullptr, 0, Fv, nullptr, 0);
    rownorm_acc<<<dim3(B_ROWS), dim3(256), 0, stream>>>(G, Fsum, D_DIM, 1);
    conv(Fsum, Fsumb, (size_t)B_ROWS * D_DIM);
    gemm(Fsumb, Ftb, B_ROWS, D_DIM, D_DIM, 4, (float*)d_out, nullptr,
         nullptr, nullptr, nullptr, nullptr, nullptr,
         nullptr, nullptr, nullptr, 0, nullptr, ls, C_CLS);
}

// Round 4
// 1206.470 us; speedup vs baseline: 9.2523x; 1.1893x over previous
//
#include <hip/hip_runtime.h>
#include <hip/hip_bf16.h>
#include <math.h>

#define D_DIM   1024
#define P_DIM   128
#define B_ROWS  4096
#define NBANK   8192
#define C_CLS   1000
#define EPS_BN  1e-5f
#define SCALE_S 0.1f
#define MTOT    20480   // 4096 + 8192 + 8192 batched pre_project rows
#define KSPLIT  4       // A@V split-K chunks

typedef __bf16 bf16x8 __attribute__((ext_vector_type(8)));
typedef float  f32x4  __attribute__((ext_vector_type(4)));

__device__ __forceinline__ void load_lds16(const void* gp, void* lp) {
    __builtin_amdgcn_global_load_lds(
        (__attribute__((address_space(1))) void*)gp,
        (__attribute__((address_space(3))) void*)lp, 16, 0, 0);
}

// ---------------------------------------------------------------------------
// bf16 MFMA GEMM: C[M,N] = A[M,K] @ B[N,K]^T (row-major bf16), 128x128 tile.
// kchunks>1: blockIdx.z selects K-chunk (split-K), epi must be 6.
// epi: 1 +bias,BN,ReLU -> bf16 | 2 batched qkv scatter (row-ranged) |
//      3 +bias + addsrc[gm & (ldc-1)] -> fp32 | 4 *exp(*lsp) -> fp32, cols<ldc |
//      5 bf16 store | 6 bf16 partial store at Cb + z*M*N
// ---------------------------------------------------------------------------
__global__ __launch_bounds__(256)
void gemm_bf16(const __hip_bfloat16* __restrict__ A,
               const __hip_bfloat16* __restrict__ B,
               int M, int N, int K, int kchunks, int epi,
               float* __restrict__ Cf, __hip_bfloat16* __restrict__ Cb,
               const float* __restrict__ bias,
               const float* __restrict__ bng, const float* __restrict__ bnb,
               const float* __restrict__ bnm, const float* __restrict__ bnv,
               __hip_bfloat16* __restrict__ qo,
               __hip_bfloat16* __restrict__ ks, __hip_bfloat16* __restrict__ kt,
               __hip_bfloat16* __restrict__ vs, __hip_bfloat16* __restrict__ vt,
               const float* __restrict__ addsrc, const float* __restrict__ lsp,
               int ldc)
{
    __shared__ __align__(16) short lsA[128 * 32];
    __shared__ __align__(16) short lsB[128 * 32];

    const int tid  = threadIdx.x;
    const int wave = tid >> 6;
    const int lane = tid & 63;
    const int wm   = wave >> 1;
    const int wn   = wave & 1;
    const int bm0  = blockIdx.y * 128;
    const int bn0  = blockIdx.x * 128;
    const int r16  = lane & 15;
    const int quad = lane >> 4;

    const int kper = K / kchunks;
    const int kbeg = blockIdx.z * kper;
    const int kend = kbeg + kper;

    f32x4 acc[4][4];
#pragma unroll
    for (int i = 0; i < 4; ++i)
#pragma unroll
        for (int j = 0; j < 4; ++j) acc[i][j] = (f32x4){0.f, 0.f, 0.f, 0.f};

    for (int k0 = kbeg; k0 < kend; k0 += 32) {
#pragma unroll
        for (int i = 0; i < 2; ++i) {
            const int s   = i * 256 + tid;
            const int row = s >> 2;
            const int cc  = (s & 3) * 8;
            const int lofs = (i * 256 + wave * 64) * 16;
            load_lds16(A + (size_t)(bm0 + row) * K + k0 + cc, (char*)lsA + lofs);
            load_lds16(B + (size_t)(bn0 + row) * K + k0 + cc, (char*)lsB + lofs);
        }
        __syncthreads();

        bf16x8 af[4], bfr[4];
#pragma unroll
        for (int i = 0; i < 4; ++i)
            af[i] = *(const bf16x8*)(lsA + (wm * 64 + i * 16 + r16) * 32 + quad * 8);
#pragma unroll
        for (int j = 0; j < 4; ++j)
            bfr[j] = *(const bf16x8*)(lsB + (wn * 64 + j * 16 + r16) * 32 + quad * 8);
#pragma unroll
        for (int i = 0; i < 4; ++i)
#pragma unroll
            for (int j = 0; j < 4; ++j)
                acc[i][j] = __builtin_amdgcn_mfma_f32_16x16x32_bf16(
                    af[i], bfr[j], acc[i][j], 0, 0, 0);
        __syncthreads();
    }

    const float lsv = (epi == 4) ? expf(*lsp) : 1.0f;

    // C/D layout: col = lane&15, row = quad*4 + reg
#pragma unroll
    for (int i = 0; i < 4; ++i) {
        const int gmb = bm0 + wm * 64 + i * 16 + quad * 4;
#pragma unroll
        for (int j = 0; j < 4; ++j) {
            const int gn = bn0 + wn * 64 + j * 16 + r16;
#pragma unroll
            for (int r = 0; r < 4; ++r) {
                const int gm = gmb + r;
                float val = acc[i][j][r];
                if (epi == 1) {
                    float x = val + bias[gn];
                    x = (x - bnm[gn]) * rsqrtf(bnv[gn] + EPS_BN) * bng[gn] + bnb[gn];
                    Cb[(size_t)gm * N + gn] = __float2bfloat16(fmaxf(x, 0.f));
                } else if (epi == 2) {
                    // rows [0,4096): q ; [4096,12288): s-bank ; [12288,20480): t-bank
                    float x = val + bias[gn];
                    int d = gn / 3, rr = gn - 3 * d;
                    __hip_bfloat16 h = __float2bfloat16(x);
                    if (rr == 0) {
                        if (gm < B_ROWS) qo[(size_t)gm * D_DIM + d] = h;
                    } else if (gm >= B_ROWS) {
                        int isS = (gm < B_ROWS + NBANK);
                        int row = isS ? (gm - B_ROWS) : (gm - B_ROWS - NBANK);
                        if (rr == 1) (isS ? ks : kt)[(size_t)row * D_DIM + d] = h;
                        else         (isS ? vs : vt)[(size_t)d * NBANK + row] = h;
                    }
                } else if (epi == 3) {
                    Cf[(size_t)gm * N + gn] =
                        val + bias[gn] + addsrc[(size_t)(gm & (ldc - 1)) * N + gn];
                } else if (epi == 4) {
                    if (gn < ldc) Cf[(size_t)gm * ldc + gn] = val * lsv;
                } else if (epi == 5) {
                    Cb[(size_t)gm * N + gn] = __float2bfloat16(val);
                } else { // 6
                    Cb[((size_t)blockIdx.z * M + gm) * N + gn] = __float2bfloat16(val);
                }
            }
        }
    }
}

// in-place row softmax over ncols bf16 (applies SCALE_S), one block per row
__global__ __launch_bounds__(256)
void softmax_bf16(__hip_bfloat16* __restrict__ S, int ncols)
{
    __shared__ float buf[NBANK];
    __shared__ float red[8];
    const int tid = threadIdx.x;
    __hip_bfloat16* p = S + (size_t)blockIdx.x * ncols;

    float mx = -1e30f;
    for (int i = tid; i < ncols; i += 256) {
        float x = SCALE_S * __bfloat162float(p[i]);
        buf[i] = x;
        mx = fmaxf(mx, x);
    }
    for (int s = 32; s > 0; s >>= 1) mx = fmaxf(mx, __shfl_down(mx, s, 64));
    if ((tid & 63) == 0) red[tid >> 6] = mx;
    __syncthreads();
    if (tid == 0) {
        float t = red[0];
        for (int w = 1; w < 4; ++w) t = fmaxf(t, red[w]);
        red[4] = t;
    }
    __syncthreads();
    mx = red[4];

    float sum = 0.f;
    for (int i = tid; i < ncols; i += 256) {
        float e = expf(buf[i] - mx);
        buf[i] = e;
        sum += e;
    }
    for (int s = 32; s > 0; s >>= 1) sum += __shfl_down(sum, s, 64);
    __syncthreads();
    if ((tid & 63) == 0) red[tid >> 6] = sum;
    __syncthreads();
    if (tid == 0) {
        float t = 0.f;
        for (int w = 0; w < 4; ++w) t += red[w];
        red[5] = t;
    }
    __syncthreads();
    const float inv = 1.0f / red[5];
    for (int i = tid; i < ncols; i += 256) p[i] = __float2bfloat16(buf[i] * inv);
}

// sum KSPLIT bf16 partials (stride psz) -> bf16, 8 elems/thread
__global__ __launch_bounds__(256)
void reduce_parts(const __hip_bfloat16* __restrict__ parts, size_t psz,
                  __hip_bfloat16* __restrict__ out, int n)
{
    int i = (blockIdx.x * 256 + threadIdx.x) * 8;
    if (i + 8 > n) return;
    float s[8] = {};
#pragma unroll
    for (int z = 0; z < KSPLIT; ++z) {
        union { int4 v; __hip_bfloat16 h[8]; } u;
        u.v = *(const int4*)(parts + z * psz + i);
#pragma unroll
        for (int e = 0; e < 8; ++e) s[e] += __bfloat162float(u.h[e]);
    }
    union { int4 v; __hip_bfloat16 h[8]; } o;
#pragma unroll
    for (int e = 0; e < 8; ++e) o.h[e] = __float2bfloat16(s[e]);
    *(int4*)(out + i) = o.v;
}

// dual row L2-normalize: Fsum[r] = Gs[r]/||Gs[r]|| + Gt[r]/||Gt[r]||
// G holds 8192 rows: [0,4096) = s-side, [4096,8192) = t-side
__global__ __launch_bounds__(256)
void rownorm2(const float* __restrict__ G, float* __restrict__ Fsum)
{
    __shared__ float red[16];
    const int tid = threadIdx.x;
    const float* ps = G + (size_t)blockIdx.x * D_DIM;
    const float* pt = ps + (size_t)B_ROWS * D_DIM;
    float sa = 0.f, sb = 0.f;
    for (int i = tid; i < D_DIM; i += 256) {
        float a = ps[i], b = pt[i];
        sa = fmaf(a, a, sa); sb = fmaf(b, b, sb);
    }
    for (int s = 32; s > 0; s >>= 1) {
        sa += __shfl_down(sa, s, 64);
        sb += __shfl_down(sb, s, 64);
    }
    if ((tid & 63) == 0) { red[tid >> 6] = sa; red[8 + (tid >> 6)] = sb; }
    __syncthreads();
    if (tid == 0) {
        float ta = 0.f, tb = 0.f;
        for (int w = 0; w < 4; ++w) { ta += red[w]; tb += red[8 + w]; }
        red[4] = rsqrtf(ta); red[12] = rsqrtf(tb);
    }
    __syncthreads();
    const float ia = red[4], ib = red[12];
    float* o = Fsum + (size_t)blockIdx.x * D_DIM;
    for (int i = tid; i < D_DIM; i += 256) o[i] = ps[i] * ia + pt[i] * ib;
}

// concat-convert Fv|Fvs|Fvt -> Xb (bf16), 8/thread
__global__ __launch_bounds__(256)
void convX(const float* __restrict__ Fv, const float* __restrict__ Fvs,
           const float* __restrict__ Fvt, __hip_bfloat16* __restrict__ X)
{
    int i = (blockIdx.x * 256 + threadIdx.x) * 8;
    const int n0 = B_ROWS * D_DIM, n1 = n0 + NBANK * D_DIM;
    const float* src;
    int off;
    if (i < n0)      { src = Fv;  off = i; }
    else if (i < n1) { src = Fvs; off = i - n0; }
    else             { src = Fvt; off = i - n1; }
    float4 a = *(const float4*)(src + off);
    float4 b = *(const float4*)(src + off + 4);
    union { __hip_bfloat16 h[8]; int4 v; } u;
    u.h[0] = __float2bfloat16(a.x); u.h[1] = __float2bfloat16(a.y);
    u.h[2] = __float2bfloat16(a.z); u.h[3] = __float2bfloat16(a.w);
    u.h[4] = __float2bfloat16(b.x); u.h[5] = __float2bfloat16(b.y);
    u.h[6] = __float2bfloat16(b.z); u.h[7] = __float2bfloat16(b.w);
    *(int4*)(X + i) = u.v;
}

// convert W1|W2|W3|Wp (fp32) -> separate bf16 buffers, 8/thread
__global__ __launch_bounds__(256)
void convW(const float* __restrict__ W1, const float* __restrict__ W2,
           const float* __restrict__ W3, const float* __restrict__ Wp,
           __hip_bfloat16* __restrict__ W1b, __hip_bfloat16* __restrict__ W2b,
           __hip_bfloat16* __restrict__ W3b, __hip_bfloat16* __restrict__ Wpb)
{
    int i = (blockIdx.x * 256 + threadIdx.x) * 8;
    const int n1 = P_DIM * D_DIM;            // 131072
    const int n2 = n1 + P_DIM * P_DIM;       // 147456
    const int n3 = n2 + 3 * D_DIM * P_DIM;   // 540672
    const float* src; __hip_bfloat16* dst; int off;
    if (i < n1)      { src = W1; dst = W1b; off = i; }
    else if (i < n2) { src = W2; dst = W2b; off = i - n1; }
    else if (i < n3) { src = W3; dst = W3b; off = i - n2; }
    else             { src = Wp; dst = Wpb; off = i - n3; }
    float4 a = *(const float4*)(src + off);
    float4 b = *(const float4*)(src + off + 4);
    union { __hip_bfloat16 h[8]; int4 v; } u;
    u.h[0] = __float2bfloat16(a.x); u.h[1] = __float2bfloat16(a.y);
    u.h[2] = __float2bfloat16(a.z); u.h[3] = __float2bfloat16(a.w);
    u.h[4] = __float2bfloat16(b.x); u.h[5] = __float2bfloat16(b.y);
    u.h[6] = __float2bfloat16(b.z); u.h[7] = __float2bfloat16(b.w);
    *(int4*)(dst + off) = u.v;
}

// fp32 -> bf16, 8/thread
__global__ __launch_bounds__(256)
void f2b(const float* __restrict__ in, __hip_bfloat16* __restrict__ out, int n)
{
    int i = (blockIdx.x * 256 + threadIdx.x) * 8;
    if (i + 8 > n) return;
    float4 a = *(const float4*)(in + i);
    float4 b = *(const float4*)(in + i + 4);
    union { __hip_bfloat16 h[8]; int4 v; } u;
    u.h[0] = __float2bfloat16(a.x); u.h[1] = __float2bfloat16(a.y);
    u.h[2] = __float2bfloat16(a.z); u.h[3] = __float2bfloat16(a.w);
    u.h[4] = __float2bfloat16(b.x); u.h[5] = __float2bfloat16(b.y);
    u.h[6] = __float2bfloat16(b.z); u.h[7] = __float2bfloat16(b.w);
    *(int4*)(out + i) = u.v;
}

// Ft [1000,1024] fp32 -> [1024,1024] bf16, rows 1000..1023 zero
__global__ __launch_bounds__(256)
void ftpad(const float* __restrict__ Ft, __hip_bfloat16* __restrict__ out)
{
    int idx = blockIdx.x * 256 + threadIdx.x;
    int row = idx >> 10, col = idx & 1023;
    float v = (row < C_CLS) ? Ft[(size_t)row * D_DIM + col] : 0.f;
    out[idx] = __float2bfloat16(v);
}

extern "C" void kernel_launch(void* const* d_in, const int* in_sizes, int n_in,
                              void* d_out, int out_size, void* d_ws, size_t ws_size,
                              hipStream_t stream)
{
    (void)in_sizes; (void)n_in; (void)out_size; (void)ws_size;

    const float* Ft  = (const float*)d_in[0];
    const float* Fv  = (const float*)d_in[1];
    const float* Fvs = (const float*)d_in[2];
    const float* Fvt = (const float*)d_in[3];
    const float* W1  = (const float*)d_in[4];
    const float* b1  = (const float*)d_in[5];
    const float* g1  = (const float*)d_in[6];
    const float* be1 = (const float*)d_in[7];
    const float* m1  = (const float*)d_in[8];
    const float* v1  = (const float*)d_in[9];
    const float* W2  = (const float*)d_in[10];
    const float* b2  = (const float*)d_in[11];
    const float* g2  = (const float*)d_in[12];
    const float* be2 = (const float*)d_in[13];
    const float* m2  = (const float*)d_in[14];
    const float* v2  = (const float*)d_in[15];
    const float* W3  = (const float*)d_in[16];
    const float* b3  = (const float*)d_in[17];
    const float* Wp  = (const float*)d_in[18];
    const float* bp  = (const float*)d_in[19];
    const float* ls  = (const float*)d_in[20];

    typedef __hip_bfloat16 bf;
    char* base = (char*)d_ws;
    size_t o = 0;
    auto take = [&](size_t s) { size_t r = o; o += (s + 255) & ~(size_t)255; return r; };

    // persistent (~92 MB)
    bf* qb   = (bf*)(base + take((size_t)B_ROWS * D_DIM * 2));
    bf* ksb  = (bf*)(base + take((size_t)NBANK * D_DIM * 2));
    bf* ktb  = (bf*)(base + take((size_t)NBANK * D_DIM * 2));
    bf* vsT  = (bf*)(base + take((size_t)D_DIM * NBANK * 2));
    bf* vtT  = (bf*)(base + take((size_t)D_DIM * NBANK * 2));
    bf* Yst  = (bf*)(base + take((size_t)2 * B_ROWS * D_DIM * 2)); // [Ys; Yt]
    bf* Wpb  = (bf*)(base + take((size_t)D_DIM * D_DIM * 2));
    bf* Ftb  = (bf*)(base + take((size_t)D_DIM * D_DIM * 2));
    bf* Ysb  = Yst;
    bf* Ytb  = Yst + (size_t)B_ROWS * D_DIM;

    // region D (aliased, max 96 MB)
    size_t Dbase = o;
    // P2 view
    size_t p = Dbase;
    auto take2 = [&](size_t s) { size_t r = p; p += (s + 255) & ~(size_t)255; return r; };
    bf* Xb  = (bf*)(base + take2((size_t)MTOT * D_DIM * 2));
    bf* h1b = (bf*)(base + take2((size_t)MTOT * P_DIM * 2));
    bf* h2b = (bf*)(base + take2((size_t)MTOT * P_DIM * 2));
    bf* W1b = (bf*)(base + take2((size_t)P_DIM * D_DIM * 2));
    bf* W2b = (bf*)(base + take2((size_t)P_DIM * P_DIM * 2));
    bf* W3b = (bf*)(base + take2((size_t)3 * D_DIM * P_DIM * 2));
    // P3 view: S (64 MB) + split-K partials (32 MB)
    bf* Sb    = (bf*)(base + Dbase);
    bf* Opart = (bf*)(base + Dbase + (size_t)B_ROWS * NBANK * 2);
    // P4 view: G (32 MB) + Fsum (16 MB) + Fsumb (8 MB)
    float* G     = (float*)(base + Dbase);
    float* Fsum  = (float*)(base + Dbase + (size_t)2 * B_ROWS * D_DIM * 4);
    bf*    Fsumb = (bf*)(base + Dbase + (size_t)3 * B_ROWS * D_DIM * 4);

    auto gemm = [&](const bf* A, const bf* B, int M, int N, int K, int kch,
                    int epi, float* Cf, bf* Cb, const float* bias,
                    const float* bg, const float* bb, const float* bm, const float* bv,
                    bf* qo, bf* ks, bf* kt, bf* vs, bf* vt,
                    const float* addsrc, const float* lsp, int ldc) {
        gemm_bf16<<<dim3(N / 128, M / 128, kch), dim3(256), 0, stream>>>(
            A, B, M, N, K, kch, epi, Cf, Cb, bias, bg, bb, bm, bv,
            qo, ks, kt, vs, vt, addsrc, lsp, ldc);
    };

    // P1: conversions (3 launches)
    convX<<<dim3(MTOT * D_DIM / 2048), dim3(256), 0, stream>>>(Fv, Fvs, Fvt, Xb);
    convW<<<dim3(776), dim3(256), 0, stream>>>(W1, W2, W3, Wp, W1b, W2b, W3b, Wpb);
    ftpad<<<dim3(D_DIM * D_DIM / 256), dim3(256), 0, stream>>>(Ft, Ftb);

    // P2: batched pre_project over X = [Fv; Fvs; Fvt]  (3 GEMMs)
    gemm(Xb, W1b, MTOT, P_DIM, D_DIM, 1, 1, nullptr, h1b, b1, g1, be1, m1, v1,
         nullptr, nullptr, nullptr, nullptr, nullptr, nullptr, nullptr, 0);
    gemm(h1b, W2b, MTOT, P_DIM, P_DIM, 1, 1, nullptr, h2b, b2, g2, be2, m2, v2,
         nullptr, nullptr, nullptr, nullptr, nullptr, nullptr, nullptr, 0);
    gemm(h2b, W3b, MTOT, 3 * D_DIM, P_DIM, 1, 2, nullptr, nullptr, b3,
         nullptr, nullptr, nullptr, nullptr,
         qb, ksb, ktb, vsT, vtT, nullptr, nullptr, 0);

    // P3: attention per side: QK^T -> softmax -> split-K A@V -> reduce
    for (int side = 0; side < 2; ++side) {
        const bf* kb = side ? ktb : ksb;
        const bf* vT = side ? vtT : vsT;
        bf* Yb = side ? Ytb : Ysb;
        gemm(qb, kb, B_ROWS, NBANK, D_DIM, 1, 5, nullptr, Sb,
             nullptr, nullptr, nullptr, nullptr, nullptr,
             nullptr, nullptr, nullptr, nullptr, nullptr, nullptr, nullptr, 0);
        softmax_bf16<<<dim3(B_ROWS), dim3(256), 0, stream>>>(Sb, NBANK);
        gemm(Sb, vT, B_ROWS, D_DIM, NBANK, KSPLIT, 6, nullptr, Opart,
             nullptr, nullptr, nullptr, nullptr, nullptr,
             nullptr, nullptr, nullptr, nullptr, nullptr, nullptr, nullptr, 0);
        reduce_parts<<<dim3(B_ROWS * D_DIM / 2048), dim3(256), 0, stream>>>(
            Opart, (size_t)B_ROWS * D_DIM, Yb, B_ROWS * D_DIM);
    }

    // P4: combined post-project (M=8192) + dual rownorm + logits
    gemm(Yst, Wpb, 2 * B_ROWS, D_DIM, D_DIM, 1, 3, G, nullptr, bp,
         nullptr, nullptr, nullptr, nullptr,
         nullptr, nullptr, nullptr, nullptr, nullptr, Fv, nullptr, B_ROWS);
    rownorm2<<<dim3(B_ROWS), dim3(256), 0, stream>>>(G, Fsum);
    f2b<<<dim3(B_ROWS * D_DIM / 2048), dim3(256), 0, stream>>>(
        Fsum, Fsumb, B_ROWS * D_DIM);
    gemm(Fsumb, Ftb, B_ROWS, D_DIM, D_DIM, 1, 4, (float*)d_out, nullptr,
         nullptr, nullptr, nullptr, nullptr, nullptr,
         nullptr, nullptr, nullptr, nullptr, nullptr, nullptr, ls, C_CLS);
}

// Round 5
// 967.031 us; speedup vs baseline: 11.5432x; 1.2476x over previous
//
#include <hip/hip_runtime.h>
#include <hip/hip_bf16.h>
#include <math.h>

#define D_DIM   1024
#define P_DIM   128
#define B_ROWS  4096
#define NBANK   8192
#define C_CLS   1000
#define EPS_BN  1e-5f
#define SCALE_S 0.1f
#define MTOT    20480   // 4096 + 8192 + 8192 batched pre_project rows
#define KSPLIT  4       // A@V split-K chunks

typedef __bf16 bf16x8 __attribute__((ext_vector_type(8)));
typedef float  f32x4  __attribute__((ext_vector_type(4)));
typedef __hip_bfloat16 bf;

__device__ __forceinline__ void load_lds16(const void* gp, void* lp) {
    __builtin_amdgcn_global_load_lds(
        (__attribute__((address_space(1))) void*)gp,
        (__attribute__((address_space(3))) void*)lp, 16, 0, 0);
}

// ---------------------------------------------------------------------------
// bf16 MFMA GEMM: C[M,N] = A[M,K] @ B[N,K]^T (row-major bf16), 128x128 tile.
// A row stride = K; B row stride = ldb. kchunks>1 -> split-K via blockIdx.z.
// epi: 1 +bias,BN,ReLU -> bf16 | 3 fp32 +bias + addsrc[(gm&(ldc-1))*N+gn] |
//      4 fp32 *exp(*lsp), cols<ldc | 5 bf16 (+bias[n], +biasm[m]) |
//      6 bf16 partial at Cb + z*M*N
// bf16 epis (1,5,6) store via per-wave LDS staging -> dwordx4 coalesced.
// ---------------------------------------------------------------------------
__global__ __launch_bounds__(256)
void gemm_bf16(const bf* __restrict__ A, const bf* __restrict__ B,
               int M, int N, int K, int ldb, int kchunks, int epi,
               float* __restrict__ Cf, bf* __restrict__ Cb,
               const float* __restrict__ bias, const float* __restrict__ biasm,
               const float* __restrict__ bng, const float* __restrict__ bnb,
               const float* __restrict__ bnm, const float* __restrict__ bnv,
               const float* __restrict__ addsrc, const float* __restrict__ lsp,
               int ldc)
{
    __shared__ __align__(16) short ldsS[8192];   // 16 KB
    short* lsA = ldsS;          // [128][32]
    short* lsB = ldsS + 4096;   // [128][32]

    const int tid  = threadIdx.x;
    const int wave = tid >> 6;
    const int lane = tid & 63;
    const int wm   = wave >> 1;
    const int wn   = wave & 1;
    const int bm0  = blockIdx.y * 128;
    const int bn0  = blockIdx.x * 128;
    const int r16  = lane & 15;
    const int quad = lane >> 4;

    const int kper = K / kchunks;
    const int kbeg = blockIdx.z * kper;
    const int kend = kbeg + kper;

    f32x4 acc[4][4];
#pragma unroll
    for (int i = 0; i < 4; ++i)
#pragma unroll
        for (int j = 0; j < 4; ++j) acc[i][j] = (f32x4){0.f, 0.f, 0.f, 0.f};

    for (int k0 = kbeg; k0 < kend; k0 += 32) {
#pragma unroll
        for (int i = 0; i < 2; ++i) {
            const int s   = i * 256 + tid;
            const int row = s >> 2;
            const int cc  = (s & 3) * 8;
            const int lofs = (i * 256 + wave * 64) * 16;
            load_lds16(A + (size_t)(bm0 + row) * K + k0 + cc, (char*)lsA + lofs);
            load_lds16(B + (size_t)(bn0 + row) * ldb + k0 + cc, (char*)lsB + lofs);
        }
        __syncthreads();

        bf16x8 af[4], bfr[4];
#pragma unroll
        for (int i = 0; i < 4; ++i)
            af[i] = *(const bf16x8*)(lsA + (wm * 64 + i * 16 + r16) * 32 + quad * 8);
#pragma unroll
        for (int j = 0; j < 4; ++j)
            bfr[j] = *(const bf16x8*)(lsB + (wn * 64 + j * 16 + r16) * 32 + quad * 8);
#pragma unroll
        for (int i = 0; i < 4; ++i)
#pragma unroll
            for (int j = 0; j < 4; ++j)
                acc[i][j] = __builtin_amdgcn_mfma_f32_16x16x32_bf16(
                    af[i], bfr[j], acc[i][j], 0, 0, 0);
        __syncthreads();
    }
    // after final barrier all LDS fragment reads are complete -> safe to reuse

    if (epi == 3 || epi == 4) {
        const float lsv = (epi == 4) ? expf(*lsp) : 1.0f;
#pragma unroll
        for (int i = 0; i < 4; ++i) {
            const int gmb = bm0 + wm * 64 + i * 16 + quad * 4;
#pragma unroll
            for (int j = 0; j < 4; ++j) {
                const int gn = bn0 + wn * 64 + j * 16 + r16;
#pragma unroll
                for (int r = 0; r < 4; ++r) {
                    const int gm = gmb + r;
                    float val = acc[i][j][r];
                    if (epi == 3) {
                        Cf[(size_t)gm * N + gn] =
                            val + bias[gn] + addsrc[(size_t)(gm & (ldc - 1)) * N + gn];
                    } else {
                        if (gn < ldc) Cf[(size_t)gm * ldc + gn] = val * lsv;
                    }
                }
            }
        }
        return;
    }

    // bf16 LDS-staged store path (epi 1, 5, 6)
    bf* dst = Cb + (epi == 6 ? (size_t)blockIdx.z * M * N : 0);
    bf* my  = (bf*)(ldsS + wave * 2048);   // 4 KB per wave: [32][64] bf16

#pragma unroll
    for (int half = 0; half < 2; ++half) {
#pragma unroll
        for (int i2 = 0; i2 < 2; ++i2) {
            const int i = half * 2 + i2;
            const int gmb = bm0 + wm * 64 + i * 16 + quad * 4;
#pragma unroll
            for (int j = 0; j < 4; ++j) {
                const int gn = bn0 + wn * 64 + j * 16 + r16;
#pragma unroll
                for (int r = 0; r < 4; ++r) {
                    float val = acc[i][j][r];
                    if (epi == 1) {
                        val += bias[gn];
                        val = (val - bnm[gn]) * rsqrtf(bnv[gn] + EPS_BN) * bng[gn] + bnb[gn];
                        val = fmaxf(val, 0.f);
                    } else {
                        if (bias)  val += bias[gn];
                        if (biasm) val += biasm[gmb + r];
                    }
                    my[(i2 * 16 + quad * 4 + r) * 64 + j * 16 + r16] =
                        __float2bfloat16(val);
                }
            }
        }
#pragma unroll
        for (int it = 0; it < 4; ++it) {
            const int chunk = it * 64 + lane;
            const int lrow  = chunk >> 3;
            const int lcol  = (chunk & 7) * 8;
            const int grow  = bm0 + wm * 64 + half * 32 + lrow;
            const int gcol  = bn0 + wn * 64 + lcol;
            int4 v = *(const int4*)(my + lrow * 64 + lcol);
            *(int4*)(dst + (size_t)grow * N + gcol) = v;
        }
    }
}

// in-place row softmax over ncols bf16 (applies SCALE_S), one block per row
__global__ __launch_bounds__(256)
void softmax_bf16(bf* __restrict__ S, int ncols)
{
    __shared__ float buf[NBANK];
    __shared__ float red[8];
    const int tid = threadIdx.x;
    bf* p = S + (size_t)blockIdx.x * ncols;

    float mx = -1e30f;
    for (int i = tid; i < ncols; i += 256) {
        float x = SCALE_S * __bfloat162float(p[i]);
        buf[i] = x;
        mx = fmaxf(mx, x);
    }
    for (int s = 32; s > 0; s >>= 1) mx = fmaxf(mx, __shfl_down(mx, s, 64));
    if ((tid & 63) == 0) red[tid >> 6] = mx;
    __syncthreads();
    if (tid == 0) {
        float t = red[0];
        for (int w = 1; w < 4; ++w) t = fmaxf(t, red[w]);
        red[4] = t;
    }
    __syncthreads();
    mx = red[4];

    float sum = 0.f;
    for (int i = tid; i < ncols; i += 256) {
        float e = expf(buf[i] - mx);
        buf[i] = e;
        sum += e;
    }
    for (int s = 32; s > 0; s >>= 1) sum += __shfl_down(sum, s, 64);
    __syncthreads();
    if ((tid & 63) == 0) red[tid >> 6] = sum;
    __syncthreads();
    if (tid == 0) {
        float t = 0.f;
        for (int w = 0; w < 4; ++w) t += red[w];
        red[5] = t;
    }
    __syncthreads();
    const float inv = 1.0f / red[5];
    for (int i = tid; i < ncols; i += 256) p[i] = __float2bfloat16(buf[i] * inv);
}

// sum KSPLIT bf16 partials (stride psz) -> bf16, 8 elems/thread
__global__ __launch_bounds__(256)
void reduce_parts(const bf* __restrict__ parts, size_t psz,
                  bf* __restrict__ out, int n)
{
    int i = (blockIdx.x * 256 + threadIdx.x) * 8;
    if (i + 8 > n) return;
    float s[8] = {};
#pragma unroll
    for (int z = 0; z < KSPLIT; ++z) {
        union { int4 v; bf h[8]; } u;
        u.v = *(const int4*)(parts + z * psz + i);
#pragma unroll
        for (int e = 0; e < 8; ++e) s[e] += __bfloat162float(u.h[e]);
    }
    union { int4 v; bf h[8]; } o;
#pragma unroll
    for (int e = 0; e < 8; ++e) o.h[e] = __float2bfloat16(s[e]);
    *(int4*)(out + i) = o.v;
}

// dual row L2-normalize: Fsum[r] = Gs[r]/||Gs[r]|| + Gt[r]/||Gt[r]||
__global__ __launch_bounds__(256)
void rownorm2(const float* __restrict__ G, float* __restrict__ Fsum)
{
    __shared__ float red[16];
    const int tid = threadIdx.x;
    const float* ps = G + (size_t)blockIdx.x * D_DIM;
    const float* pt = ps + (size_t)B_ROWS * D_DIM;
    float sa = 0.f, sb = 0.f;
    for (int i = tid; i < D_DIM; i += 256) {
        float a = ps[i], b = pt[i];
        sa = fmaf(a, a, sa); sb = fmaf(b, b, sb);
    }
    for (int s = 32; s > 0; s >>= 1) {
        sa += __shfl_down(sa, s, 64);
        sb += __shfl_down(sb, s, 64);
    }
    if ((tid & 63) == 0) { red[tid >> 6] = sa; red[8 + (tid >> 6)] = sb; }
    __syncthreads();
    if (tid == 0) {
        float ta = 0.f, tb = 0.f;
        for (int w = 0; w < 4; ++w) { ta += red[w]; tb += red[8 + w]; }
        red[4] = rsqrtf(ta); red[12] = rsqrtf(tb);
    }
    __syncthreads();
    const float ia = red[4], ib = red[12];
    float* o = Fsum + (size_t)blockIdx.x * D_DIM;
    for (int i = tid; i < D_DIM; i += 256) o[i] = ps[i] * ia + pt[i] * ib;
}

// concat-convert Fv|Fvs|Fvt -> Xb (bf16), 8/thread
__global__ __launch_bounds__(256)
void convX(const float* __restrict__ Fv, const float* __restrict__ Fvs,
           const float* __restrict__ Fvt, bf* __restrict__ X)
{
    int i = (blockIdx.x * 256 + threadIdx.x) * 8;
    const int n0 = B_ROWS * D_DIM, n1 = n0 + NBANK * D_DIM;
    const float* src;
    int off;
    if (i < n0)      { src = Fv;  off = i; }
    else if (i < n1) { src = Fvs; off = i - n0; }
    else             { src = Fvt; off = i - n1; }
    float4 a = *(const float4*)(src + off);
    float4 b = *(const float4*)(src + off + 4);
    union { bf h[8]; int4 v; } u;
    u.h[0] = __float2bfloat16(a.x); u.h[1] = __float2bfloat16(a.y);
    u.h[2] = __float2bfloat16(a.z); u.h[3] = __float2bfloat16(a.w);
    u.h[4] = __float2bfloat16(b.x); u.h[5] = __float2bfloat16(b.y);
    u.h[6] = __float2bfloat16(b.z); u.h[7] = __float2bfloat16(b.w);
    *(int4*)(X + i) = u.v;
}

// convert W1|W2|Wp -> bf16, 8/thread
__global__ __launch_bounds__(256)
void convW(const float* __restrict__ W1, const float* __restrict__ W2,
           const float* __restrict__ Wp,
           bf* __restrict__ W1b, bf* __restrict__ W2b, bf* __restrict__ Wpb)
{
    int i = (blockIdx.x * 256 + threadIdx.x) * 8;
    const int n1 = P_DIM * D_DIM;           // 131072
    const int n2 = n1 + P_DIM * P_DIM;      // 147456
    const int n3 = n2 + D_DIM * D_DIM;      // 1196032
    if (i >= n3) return;
    const float* src; bf* dst; int off;
    if (i < n1)      { src = W1; dst = W1b; off = i; }
    else if (i < n2) { src = W2; dst = W2b; off = i - n1; }
    else             { src = Wp; dst = Wpb; off = i - n2; }
    float4 a = *(const float4*)(src + off);
    float4 b = *(const float4*)(src + off + 4);
    union { bf h[8]; int4 v; } u;
    u.h[0] = __float2bfloat16(a.x); u.h[1] = __float2bfloat16(a.y);
    u.h[2] = __float2bfloat16(a.z); u.h[3] = __float2bfloat16(a.w);
    u.h[4] = __float2bfloat16(b.x); u.h[5] = __float2bfloat16(b.y);
    u.h[6] = __float2bfloat16(b.z); u.h[7] = __float2bfloat16(b.w);
    *(int4*)(dst + off) = u.v;
}

// pack W3 (3072x128 fp32) into W3q/W3k/W3v (1024x128 bf16, rows 3d+rr) + b3 split
__global__ __launch_bounds__(256)
void convW3(const float* __restrict__ W3, const float* __restrict__ b3,
            bf* __restrict__ W3q, bf* __restrict__ W3k, bf* __restrict__ W3v,
            float* __restrict__ b3q, float* __restrict__ b3k, float* __restrict__ b3v)
{
    int gid = blockIdx.x * 256 + threadIdx.x;
    int i = gid * 8;
    if (i < D_DIM * P_DIM) {
        int d = i >> 7, p = i & 127;
#pragma unroll
        for (int rr = 0; rr < 3; ++rr) {
            const float* src = W3 + (size_t)(3 * d + rr) * P_DIM + p;
            bf* dst = (rr == 0 ? W3q : rr == 1 ? W3k : W3v) + i;
            float4 a = *(const float4*)src;
            float4 b = *(const float4*)(src + 4);
            union { bf h[8]; int4 v; } u;
            u.h[0] = __float2bfloat16(a.x); u.h[1] = __float2bfloat16(a.y);
            u.h[2] = __float2bfloat16(a.z); u.h[3] = __float2bfloat16(a.w);
            u.h[4] = __float2bfloat16(b.x); u.h[5] = __float2bfloat16(b.y);
            u.h[6] = __float2bfloat16(b.z); u.h[7] = __float2bfloat16(b.w);
            *(int4*)dst = u.v;
        }
    }
    if (gid < D_DIM) {
        b3q[gid] = b3[3 * gid];
        b3k[gid] = b3[3 * gid + 1];
        b3v[gid] = b3[3 * gid + 2];
    }
}

// fp32 -> bf16, 8/thread
__global__ __launch_bounds__(256)
void f2b(const float* __restrict__ in, bf* __restrict__ out, int n)
{
    int i = (blockIdx.x * 256 + threadIdx.x) * 8;
    if (i + 8 > n) return;
    float4 a = *(const float4*)(in + i);
    float4 b = *(const float4*)(in + i + 4);
    union { bf h[8]; int4 v; } u;
    u.h[0] = __float2bfloat16(a.x); u.h[1] = __float2bfloat16(a.y);
    u.h[2] = __float2bfloat16(a.z); u.h[3] = __float2bfloat16(a.w);
    u.h[4] = __float2bfloat16(b.x); u.h[5] = __float2bfloat16(b.y);
    u.h[6] = __float2bfloat16(b.z); u.h[7] = __float2bfloat16(b.w);
    *(int4*)(out + i) = u.v;
}

// Ft [1000,1024] fp32 -> [1024,1024] bf16, rows 1000..1023 zero
__global__ __launch_bounds__(256)
void ftpad(const float* __restrict__ Ft, bf* __restrict__ out)
{
    int idx = blockIdx.x * 256 + threadIdx.x;
    int row = idx >> 10, col = idx & 1023;
    float v = (row < C_CLS) ? Ft[(size_t)row * D_DIM + col] : 0.f;
    out[idx] = __float2bfloat16(v);
}

extern "C" void kernel_launch(void* const* d_in, const int* in_sizes, int n_in,
                              void* d_out, int out_size, void* d_ws, size_t ws_size,
                              hipStream_t stream)
{
    (void)in_sizes; (void)n_in; (void)out_size; (void)ws_size;

    const float* Ft  = (const float*)d_in[0];
    const float* Fv  = (const float*)d_in[1];
    const float* Fvs = (const float*)d_in[2];
    const float* Fvt = (const float*)d_in[3];
    const float* W1  = (const float*)d_in[4];
    const float* b1  = (const float*)d_in[5];
    const float* g1  = (const float*)d_in[6];
    const float* be1 = (const float*)d_in[7];
    const float* m1  = (const float*)d_in[8];
    const float* v1  = (const float*)d_in[9];
    const float* W2  = (const float*)d_in[10];
    const float* b2  = (const float*)d_in[11];
    const float* g2  = (const float*)d_in[12];
    const float* be2 = (const float*)d_in[13];
    const float* m2  = (const float*)d_in[14];
    const float* v2  = (const float*)d_in[15];
    const float* W3  = (const float*)d_in[16];
    const float* b3  = (const float*)d_in[17];
    const float* Wp  = (const float*)d_in[18];
    const float* bp  = (const float*)d_in[19];
    const float* ls  = (const float*)d_in[20];

    char* base = (char*)d_ws;
    size_t o = 0;
    auto take = [&](size_t s) { size_t r = o; o += (s + 255) & ~(size_t)255; return r; };

    // persistent (~94 MB)
    bf* qb    = (bf*)(base + take((size_t)B_ROWS * D_DIM * 2));
    bf* kall  = (bf*)(base + take((size_t)2 * NBANK * D_DIM * 2));   // [16384,1024]
    bf* vTall = (bf*)(base + take((size_t)D_DIM * 2 * NBANK * 2));   // [1024,16384]
    bf* Yst   = (bf*)(base + take((size_t)2 * B_ROWS * D_DIM * 2));  // [Ys; Yt]
    bf* Wpb   = (bf*)(base + take((size_t)D_DIM * D_DIM * 2));
    bf* Ftb   = (bf*)(base + take((size_t)D_DIM * D_DIM * 2));
    bf* W3q   = (bf*)(base + take((size_t)D_DIM * P_DIM * 2));
    bf* W3k   = (bf*)(base + take((size_t)D_DIM * P_DIM * 2));
    bf* W3v   = (bf*)(base + take((size_t)D_DIM * P_DIM * 2));
    float* b3q = (float*)(base + take(D_DIM * 4));
    float* b3k = (float*)(base + take(D_DIM * 4));
    float* b3v = (float*)(base + take(D_DIM * 4));
    bf* Ysb = Yst;
    bf* Ytb = Yst + (size_t)B_ROWS * D_DIM;

    // region D (aliased, 96 MB)
    size_t Dbase = o;
    size_t p = Dbase;
    auto take2 = [&](size_t s) { size_t r = p; p += (s + 255) & ~(size_t)255; return r; };
    bf* Xb  = (bf*)(base + take2((size_t)MTOT * D_DIM * 2));
    bf* h1b = (bf*)(base + take2((size_t)MTOT * P_DIM * 2));
    bf* h2b = (bf*)(base + take2((size_t)MTOT * P_DIM * 2));
    bf* W1b = (bf*)(base + take2((size_t)P_DIM * D_DIM * 2));
    bf* W2b = (bf*)(base + take2((size_t)P_DIM * P_DIM * 2));
    // P3 view
    bf* Sb    = (bf*)(base + Dbase);
    bf* Opart = (bf*)(base + Dbase + (size_t)B_ROWS * NBANK * 2);
    // P4 view
    float* G     = (float*)(base + Dbase);
    float* Fsum  = (float*)(base + Dbase + (size_t)2 * B_ROWS * D_DIM * 4);
    bf*    Fsumb = (bf*)(base + Dbase + (size_t)3 * B_ROWS * D_DIM * 4);

    auto gemm = [&](const bf* A, const bf* B, int M, int N, int K, int ldb,
                    int kch, int epi, float* Cf, bf* Cb,
                    const float* bias, const float* biasm,
                    const float* bg, const float* bb, const float* bm, const float* bv,
                    const float* addsrc, const float* lsp, int ldc) {
        gemm_bf16<<<dim3(N / 128, M / 128, kch), dim3(256), 0, stream>>>(
            A, B, M, N, K, ldb, kch, epi, Cf, Cb, bias, biasm,
            bg, bb, bm, bv, addsrc, lsp, ldc);
    };

    // P1: conversions
    convX<<<dim3(MTOT * D_DIM / 2048), dim3(256), 0, stream>>>(Fv, Fvs, Fvt, Xb);
    convW<<<dim3(584), dim3(256), 0, stream>>>(W1, W2, Wp, W1b, W2b, Wpb);
    convW3<<<dim3(64), dim3(256), 0, stream>>>(W3, b3, W3q, W3k, W3v, b3q, b3k, b3v);
    ftpad<<<dim3(D_DIM * D_DIM / 256), dim3(256), 0, stream>>>(Ft, Ftb);

    // P2: batched pre_project, then clean q/k/vT GEMMs (no scatter)
    gemm(Xb, W1b, MTOT, P_DIM, D_DIM, D_DIM, 1, 1, nullptr, h1b,
         b1, nullptr, g1, be1, m1, v1, nullptr, nullptr, 0);
    gemm(h1b, W2b, MTOT, P_DIM, P_DIM, P_DIM, 1, 1, nullptr, h2b,
         b2, nullptr, g2, be2, m2, v2, nullptr, nullptr, 0);
    gemm(h2b, W3q, B_ROWS, D_DIM, P_DIM, P_DIM, 1, 5, nullptr, qb,
         b3q, nullptr, nullptr, nullptr, nullptr, nullptr, nullptr, nullptr, 0);
    gemm(h2b + (size_t)B_ROWS * P_DIM, W3k, 2 * NBANK, D_DIM, P_DIM, P_DIM, 1, 5,
         nullptr, kall, b3k, nullptr, nullptr, nullptr, nullptr, nullptr,
         nullptr, nullptr, 0);
    gemm(W3v, h2b + (size_t)B_ROWS * P_DIM, D_DIM, 2 * NBANK, P_DIM, P_DIM, 1, 5,
         nullptr, vTall, nullptr, b3v, nullptr, nullptr, nullptr, nullptr,
         nullptr, nullptr, 0);

    // P3: attention per side: QK^T -> softmax -> split-K A@V -> reduce
    for (int side = 0; side < 2; ++side) {
        const bf* kb = kall + (size_t)side * NBANK * D_DIM;
        const bf* vT = vTall + (size_t)side * NBANK;
        bf* Yb = side ? Ytb : Ysb;
        gemm(qb, kb, B_ROWS, NBANK, D_DIM, D_DIM, 1, 5, nullptr, Sb,
             nullptr, nullptr, nullptr, nullptr, nullptr, nullptr,
             nullptr, nullptr, 0);
        softmax_bf16<<<dim3(B_ROWS), dim3(256), 0, stream>>>(Sb, NBANK);
        gemm(Sb, vT, B_ROWS, D_DIM, NBANK, 2 * NBANK, KSPLIT, 6, nullptr, Opart,
             nullptr, nullptr, nullptr, nullptr, nullptr, nullptr,
             nullptr, nullptr, 0);
        reduce_parts<<<dim3(B_ROWS * D_DIM / 2048), dim3(256), 0, stream>>>(
            Opart, (size_t)B_ROWS * D_DIM, Yb, B_ROWS * D_DIM);
    }

    // P4: combined post-project (M=8192) + dual rownorm + logits
    gemm(Yst, Wpb, 2 * B_ROWS, D_DIM, D_DIM, D_DIM, 1, 3, G, nullptr,
         bp, nullptr, nullptr, nullptr, nullptr, nullptr, Fv, nullptr, B_ROWS);
    rownorm2<<<dim3(B_ROWS), dim3(256), 0, stream>>>(G, Fsum);
    f2b<<<dim3(B_ROWS * D_DIM / 2048), dim3(256), 0, stream>>>(
        Fsum, Fsumb, B_ROWS * D_DIM);
    gemm(Fsumb, Ftb, B_ROWS, D_DIM, D_DIM, D_DIM, 1, 4, (float*)d_out, nullptr,
         nullptr, nullptr, nullptr, nullptr, nullptr, nullptr, nullptr, ls, C_CLS);
}

// Round 6
// 848.420 us; speedup vs baseline: 13.1569x; 1.1398x over previous
//
#include <hip/hip_runtime.h>
#include <hip/hip_bf16.h>
#include <math.h>

#define D_DIM   1024
#define P_DIM   128
#define B_ROWS  4096
#define NBANK   8192
#define C_CLS   1000
#define EPS_BN  1e-5f
#define SCALE_S 0.1f
#define MTOT    20480   // 4096 + 8192 + 8192 batched pre_project rows
#define KSPLIT  4       // A@V split-K chunks

typedef __bf16 bf16x8 __attribute__((ext_vector_type(8)));
typedef float  f32x4  __attribute__((ext_vector_type(4)));
typedef __hip_bfloat16 bf;

__device__ __forceinline__ void load_lds16(const void* gp, void* lp) {
    __builtin_amdgcn_global_load_lds(
        (__attribute__((address_space(1))) void*)gp,
        (__attribute__((address_space(3))) void*)lp, 16, 0, 0);
}

// ---------------------------------------------------------------------------
// bf16 MFMA GEMM: C[M,N] = A[M,K] @ B[N,K]^T (row-major bf16), 128x128 tile.
// A row stride = K; B row stride = ldb. kchunks>1 -> split-K via blockIdx.z.
// XCD swizzle: fx*fy must be 8; each XCD gets a (gx/fx)x(gy/fy) tile rect
// (assumes round-robin block->XCD dispatch; perf heuristic only).
// epi: 1 +bias,BN,ReLU -> bf16 | 3 fp32 +bias + addsrc[(gm&(ldc-1))*N+gn] |
//      4 fp32 *exp(*lsp), cols<ldc | 5 bf16 (+bias[n], +biasm[m]) |
//      6 bf16 partial at Cb + z*M*N | 7 bf16 exp(SCALE_S*val)
// bf16 epis (1,5,6,7) store via per-wave LDS staging -> dwordx4 coalesced.
// ---------------------------------------------------------------------------
__global__ __launch_bounds__(256)
void gemm_bf16(const bf* __restrict__ A, const bf* __restrict__ B,
               int M, int N, int K, int ldb, int kchunks, int fx, int fy, int epi,
               float* __restrict__ Cf, bf* __restrict__ Cb,
               const float* __restrict__ bias, const float* __restrict__ biasm,
               const float* __restrict__ bng, const float* __restrict__ bnb,
               const float* __restrict__ bnm, const float* __restrict__ bnv,
               const float* __restrict__ addsrc, const float* __restrict__ lsp,
               int ldc)
{
    __shared__ __align__(16) short ldsS[8192];   // 16 KB
    short* lsA = ldsS;          // [128][32]
    short* lsB = ldsS + 4096;   // [128][32]

    const int tid  = threadIdx.x;
    const int wave = tid >> 6;
    const int lane = tid & 63;
    const int wm   = wave >> 1;
    const int wn   = wave & 1;
    const int r16  = lane & 15;
    const int quad = lane >> 4;

    // XCD-aware tile remap
    const int gx = gridDim.x, gy = gridDim.y;
    const int l   = blockIdx.y * gx + blockIdx.x;
    const int xcd = l & 7;
    const int i0  = l >> 3;
    const int sx  = gx / fx, sy = gy / fy;
    const int bx  = (xcd % fx) * sx + (i0 % sx);
    const int by  = (xcd / fx) * sy + (i0 / sx);
    const int bm0 = by * 128;
    const int bn0 = bx * 128;

    const int kper = K / kchunks;
    const int kbeg = blockIdx.z * kper;
    const int kend = kbeg + kper;

    f32x4 acc[4][4];
#pragma unroll
    for (int i = 0; i < 4; ++i)
#pragma unroll
        for (int j = 0; j < 4; ++j) acc[i][j] = (f32x4){0.f, 0.f, 0.f, 0.f};

    for (int k0 = kbeg; k0 < kend; k0 += 32) {
#pragma unroll
        for (int i = 0; i < 2; ++i) {
            const int s   = i * 256 + tid;
            const int row = s >> 2;
            const int cc  = (s & 3) * 8;
            const int lofs = (i * 256 + wave * 64) * 16;
            load_lds16(A + (size_t)(bm0 + row) * K + k0 + cc, (char*)lsA + lofs);
            load_lds16(B + (size_t)(bn0 + row) * ldb + k0 + cc, (char*)lsB + lofs);
        }
        __syncthreads();

        bf16x8 af[4], bfr[4];
#pragma unroll
        for (int i = 0; i < 4; ++i)
            af[i] = *(const bf16x8*)(lsA + (wm * 64 + i * 16 + r16) * 32 + quad * 8);
#pragma unroll
        for (int j = 0; j < 4; ++j)
            bfr[j] = *(const bf16x8*)(lsB + (wn * 64 + j * 16 + r16) * 32 + quad * 8);
#pragma unroll
        for (int i = 0; i < 4; ++i)
#pragma unroll
            for (int j = 0; j < 4; ++j)
                acc[i][j] = __builtin_amdgcn_mfma_f32_16x16x32_bf16(
                    af[i], bfr[j], acc[i][j], 0, 0, 0);
        __syncthreads();
    }
    // after final barrier all LDS fragment reads are complete -> safe to reuse

    if (epi == 3 || epi == 4) {
        const float lsv = (epi == 4) ? expf(*lsp) : 1.0f;
#pragma unroll
        for (int i = 0; i < 4; ++i) {
            const int gmb = bm0 + wm * 64 + i * 16 + quad * 4;
#pragma unroll
            for (int j = 0; j < 4; ++j) {
                const int gn = bn0 + wn * 64 + j * 16 + r16;
#pragma unroll
                for (int r = 0; r < 4; ++r) {
                    const int gm = gmb + r;
                    float val = acc[i][j][r];
                    if (epi == 3) {
                        Cf[(size_t)gm * N + gn] =
                            val + bias[gn] + addsrc[(size_t)(gm & (ldc - 1)) * N + gn];
                    } else {
                        if (gn < ldc) Cf[(size_t)gm * ldc + gn] = val * lsv;
                    }
                }
            }
        }
        return;
    }

    // bf16 LDS-staged store path (epi 1, 5, 6, 7)
    bf* dst = Cb + (epi == 6 ? (size_t)blockIdx.z * M * N : 0);
    bf* my  = (bf*)(ldsS + wave * 2048);   // 4 KB per wave: [32][64] bf16

#pragma unroll
    for (int half = 0; half < 2; ++half) {
#pragma unroll
        for (int i2 = 0; i2 < 2; ++i2) {
            const int i = half * 2 + i2;
            const int gmb = bm0 + wm * 64 + i * 16 + quad * 4;
#pragma unroll
            for (int j = 0; j < 4; ++j) {
                const int gn = bn0 + wn * 64 + j * 16 + r16;
#pragma unroll
                for (int r = 0; r < 4; ++r) {
                    float val = acc[i][j][r];
                    if (epi == 1) {
                        val += bias[gn];
                        val = (val - bnm[gn]) * rsqrtf(bnv[gn] + EPS_BN) * bng[gn] + bnb[gn];
                        val = fmaxf(val, 0.f);
                    } else if (epi == 7) {
                        val = __expf(SCALE_S * val);
                    } else {
                        if (bias)  val += bias[gn];
                        if (biasm) val += biasm[gmb + r];
                    }
                    my[(i2 * 16 + quad * 4 + r) * 64 + j * 16 + r16] =
                        __float2bfloat16(val);
                }
            }
        }
#pragma unroll
        for (int it = 0; it < 4; ++it) {
            const int chunk = it * 64 + lane;
            const int lrow  = chunk >> 3;
            const int lcol  = (chunk & 7) * 8;
            const int grow  = bm0 + wm * 64 + half * 32 + lrow;
            const int gcol  = bn0 + wn * 64 + lcol;
            int4 v = *(const int4*)(my + lrow * 64 + lcol);
            *(int4*)(dst + (size_t)grow * N + gcol) = v;
        }
    }
}

// per-row sum of bf16 matrix [nrows, NBANK] -> fp32 rowsum
__global__ __launch_bounds__(256)
void rowsum_k(const bf* __restrict__ S, float* __restrict__ rs)
{
    __shared__ float red[8];
    const int tid = threadIdx.x;
    const bf* p = S + (size_t)blockIdx.x * NBANK;
    float s = 0.f;
    for (int i = tid * 8; i < NBANK; i += 2048) {
        union { int4 v; bf h[8]; } u;
        u.v = *(const int4*)(p + i);
#pragma unroll
        for (int e = 0; e < 8; ++e) s += __bfloat162float(u.h[e]);
    }
    for (int o = 32; o > 0; o >>= 1) s += __shfl_down(s, o, 64);
    if ((tid & 63) == 0) red[tid >> 6] = s;
    __syncthreads();
    if (tid == 0) {
        float t = 0.f;
        for (int w = 0; w < 4; ++w) t += red[w];
        rs[blockIdx.x] = t;
    }
}

// sum KSPLIT bf16 partials (stride psz), divide by rowsum[row] -> bf16
__global__ __launch_bounds__(256)
void reduce_parts(const bf* __restrict__ parts, size_t psz,
                  const float* __restrict__ rowsum,
                  bf* __restrict__ out, int n)
{
    int i = (blockIdx.x * 256 + threadIdx.x) * 8;
    if (i + 8 > n) return;
    const float inv = 1.0f / rowsum[i >> 10];   // D_DIM = 1024 elems/row
    float s[8] = {};
#pragma unroll
    for (int z = 0; z < KSPLIT; ++z) {
        union { int4 v; bf h[8]; } u;
        u.v = *(const int4*)(parts + z * psz + i);
#pragma unroll
        for (int e = 0; e < 8; ++e) s[e] += __bfloat162float(u.h[e]);
    }
    union { int4 v; bf h[8]; } o;
#pragma unroll
    for (int e = 0; e < 8; ++e) o.h[e] = __float2bfloat16(s[e] * inv);
    *(int4*)(out + i) = o.v;
}

// dual row L2-normalize: Fsum[r] = Gs[r]/||Gs[r]|| + Gt[r]/||Gt[r]||
__global__ __launch_bounds__(256)
void rownorm2(const float* __restrict__ G, float* __restrict__ Fsum)
{
    __shared__ float red[16];
    const int tid = threadIdx.x;
    const float* ps = G + (size_t)blockIdx.x * D_DIM;
    const float* pt = ps + (size_t)B_ROWS * D_DIM;
    float sa = 0.f, sb = 0.f;
    for (int i = tid; i < D_DIM; i += 256) {
        float a = ps[i], b = pt[i];
        sa = fmaf(a, a, sa); sb = fmaf(b, b, sb);
    }
    for (int s = 32; s > 0; s >>= 1) {
        sa += __shfl_down(sa, s, 64);
        sb += __shfl_down(sb, s, 64);
    }
    if ((tid & 63) == 0) { red[tid >> 6] = sa; red[8 + (tid >> 6)] = sb; }
    __syncthreads();
    if (tid == 0) {
        float ta = 0.f, tb = 0.f;
        for (int w = 0; w < 4; ++w) { ta += red[w]; tb += red[8 + w]; }
        red[4] = rsqrtf(ta); red[12] = rsqrtf(tb);
    }
    __syncthreads();
    const float ia = red[4], ib = red[12];
    float* o = Fsum + (size_t)blockIdx.x * D_DIM;
    for (int i = tid; i < D_DIM; i += 256) o[i] = ps[i] * ia + pt[i] * ib;
}

// concat-convert Fv|Fvs|Fvt -> Xb (bf16), 8/thread
__global__ __launch_bounds__(256)
void convX(const float* __restrict__ Fv, const float* __restrict__ Fvs,
           const float* __restrict__ Fvt, bf* __restrict__ X)
{
    int i = (blockIdx.x * 256 + threadIdx.x) * 8;
    const int n0 = B_ROWS * D_DIM, n1 = n0 + NBANK * D_DIM;
    const float* src;
    int off;
    if (i < n0)      { src = Fv;  off = i; }
    else if (i < n1) { src = Fvs; off = i - n0; }
    else             { src = Fvt; off = i - n1; }
    float4 a = *(const float4*)(src + off);
    float4 b = *(const float4*)(src + off + 4);
    union { bf h[8]; int4 v; } u;
    u.h[0] = __float2bfloat16(a.x); u.h[1] = __float2bfloat16(a.y);
    u.h[2] = __float2bfloat16(a.z); u.h[3] = __float2bfloat16(a.w);
    u.h[4] = __float2bfloat16(b.x); u.h[5] = __float2bfloat16(b.y);
    u.h[6] = __float2bfloat16(b.z); u.h[7] = __float2bfloat16(b.w);
    *(int4*)(X + i) = u.v;
}

// convert W1|W2|Wp -> bf16, 8/thread
__global__ __launch_bounds__(256)
void convW(const float* __restrict__ W1, const float* __restrict__ W2,
           const float* __restrict__ Wp,
           bf* __restrict__ W1b, bf* __restrict__ W2b, bf* __restrict__ Wpb)
{
    int i = (blockIdx.x * 256 + threadIdx.x) * 8;
    const int n1 = P_DIM * D_DIM;           // 131072
    const int n2 = n1 + P_DIM * P_DIM;      // 147456
    const int n3 = n2 + D_DIM * D_DIM;      // 1196032
    if (i >= n3) return;
    const float* src; bf* dst; int off;
    if (i < n1)      { src = W1; dst = W1b; off = i; }
    else if (i < n2) { src = W2; dst = W2b; off = i - n1; }
    else             { src = Wp; dst = Wpb; off = i - n2; }
    float4 a = *(const float4*)(src + off);
    float4 b = *(const float4*)(src + off + 4);
    union { bf h[8]; int4 v; } u;
    u.h[0] = __float2bfloat16(a.x); u.h[1] = __float2bfloat16(a.y);
    u.h[2] = __float2bfloat16(a.z); u.h[3] = __float2bfloat16(a.w);
    u.h[4] = __float2bfloat16(b.x); u.h[5] = __float2bfloat16(b.y);
    u.h[6] = __float2bfloat16(b.z); u.h[7] = __float2bfloat16(b.w);
    *(int4*)(dst + off) = u.v;
}

// pack W3 (3072x128 fp32) into W3q/W3k/W3v (1024x128 bf16, rows 3d+rr) + b3 split
__global__ __launch_bounds__(256)
void convW3(const float* __restrict__ W3, const float* __restrict__ b3,
            bf* __restrict__ W3q, bf* __restrict__ W3k, bf* __restrict__ W3v,
            float* __restrict__ b3q, float* __restrict__ b3k, float* __restrict__ b3v)
{
    int gid = blockIdx.x * 256 + threadIdx.x;
    int i = gid * 8;
    if (i < D_DIM * P_DIM) {
        int d = i >> 7, p = i & 127;
#pragma unroll
        for (int rr = 0; rr < 3; ++rr) {
            const float* src = W3 + (size_t)(3 * d + rr) * P_DIM + p;
            bf* dst = (rr == 0 ? W3q : rr == 1 ? W3k : W3v) + i;
            float4 a = *(const float4*)src;
            float4 b = *(const float4*)(src + 4);
            union { bf h[8]; int4 v; } u;
            u.h[0] = __float2bfloat16(a.x); u.h[1] = __float2bfloat16(a.y);
            u.h[2] = __float2bfloat16(a.z); u.h[3] = __float2bfloat16(a.w);
            u.h[4] = __float2bfloat16(b.x); u.h[5] = __float2bfloat16(b.y);
            u.h[6] = __float2bfloat16(b.z); u.h[7] = __float2bfloat16(b.w);
            *(int4*)dst = u.v;
        }
    }
    if (gid < D_DIM) {
        b3q[gid] = b3[3 * gid];
        b3k[gid] = b3[3 * gid + 1];
        b3v[gid] = b3[3 * gid + 2];
    }
}

// fp32 -> bf16, 8/thread
__global__ __launch_bounds__(256)
void f2b(const float* __restrict__ in, bf* __restrict__ out, int n)
{
    int i = (blockIdx.x * 256 + threadIdx.x) * 8;
    if (i + 8 > n) return;
    float4 a = *(const float4*)(in + i);
    float4 b = *(const float4*)(in + i + 4);
    union { bf h[8]; int4 v; } u;
    u.h[0] = __float2bfloat16(a.x); u.h[1] = __float2bfloat16(a.y);
    u.h[2] = __float2bfloat16(a.z); u.h[3] = __float2bfloat16(a.w);
    u.h[4] = __float2bfloat16(b.x); u.h[5] = __float2bfloat16(b.y);
    u.h[6] = __float2bfloat16(b.z); u.h[7] = __float2bfloat16(b.w);
    *(int4*)(out + i) = u.v;
}

// Ft [1000,1024] fp32 -> [1024,1024] bf16, rows 1000..1023 zero
__global__ __launch_bounds__(256)
void ftpad(const float* __restrict__ Ft, bf* __restrict__ out)
{
    int idx = blockIdx.x * 256 + threadIdx.x;
    int row = idx >> 10, col = idx & 1023;
    float v = (row < C_CLS) ? Ft[(size_t)row * D_DIM + col] : 0.f;
    out[idx] = __float2bfloat16(v);
}

extern "C" void kernel_launch(void* const* d_in, const int* in_sizes, int n_in,
                              void* d_out, int out_size, void* d_ws, size_t ws_size,
                              hipStream_t stream)
{
    (void)in_sizes; (void)n_in; (void)out_size; (void)ws_size;

    const float* Ft  = (const float*)d_in[0];
    const float* Fv  = (const float*)d_in[1];
    const float* Fvs = (const float*)d_in[2];
    const float* Fvt = (const float*)d_in[3];
    const float* W1  = (const float*)d_in[4];
    const float* b1  = (const float*)d_in[5];
    const float* g1  = (const float*)d_in[6];
    const float* be1 = (const float*)d_in[7];
    const float* m1  = (const float*)d_in[8];
    const float* v1  = (const float*)d_in[9];
    const float* W2  = (const float*)d_in[10];
    const float* b2  = (const float*)d_in[11];
    const float* g2  = (const float*)d_in[12];
    const float* be2 = (const float*)d_in[13];
    const float* m2  = (const float*)d_in[14];
    const float* v2  = (const float*)d_in[15];
    const float* W3  = (const float*)d_in[16];
    const float* b3  = (const float*)d_in[17];
    const float* Wp  = (const float*)d_in[18];
    const float* bp  = (const float*)d_in[19];
    const float* ls  = (const float*)d_in[20];

    char* base = (char*)d_ws;
    size_t o = 0;
    auto take = [&](size_t s) { size_t r = o; o += (s + 255) & ~(size_t)255; return r; };

    // persistent (~94 MB)
    bf* qb    = (bf*)(base + take((size_t)B_ROWS * D_DIM * 2));
    bf* kall  = (bf*)(base + take((size_t)2 * NBANK * D_DIM * 2));   // [16384,1024]
    bf* vTall = (bf*)(base + take((size_t)D_DIM * 2 * NBANK * 2));   // [1024,16384]
    bf* Yst   = (bf*)(base + take((size_t)2 * B_ROWS * D_DIM * 2));  // [Ys; Yt]
    bf* Wpb   = (bf*)(base + take((size_t)D_DIM * D_DIM * 2));
    bf* Ftb   = (bf*)(base + take((size_t)D_DIM * D_DIM * 2));
    bf* W3q   = (bf*)(base + take((size_t)D_DIM * P_DIM * 2));
    bf* W3k   = (bf*)(base + take((size_t)D_DIM * P_DIM * 2));
    bf* W3v   = (bf*)(base + take((size_t)D_DIM * P_DIM * 2));
    float* b3q = (float*)(base + take(D_DIM * 4));
    float* b3k = (float*)(base + take(D_DIM * 4));
    float* b3v = (float*)(base + take(D_DIM * 4));
    float* rsum = (float*)(base + take(B_ROWS * 4));
    bf* Ysb = Yst;
    bf* Ytb = Yst + (size_t)B_ROWS * D_DIM;

    // region D (aliased, 96 MB)
    size_t Dbase = o;
    size_t p = Dbase;
    auto take2 = [&](size_t s) { size_t r = p; p += (s + 255) & ~(size_t)255; return r; };
    bf* Xb  = (bf*)(base + take2((size_t)MTOT * D_DIM * 2));
    bf* h1b = (bf*)(base + take2((size_t)MTOT * P_DIM * 2));
    bf* h2b = (bf*)(base + take2((size_t)MTOT * P_DIM * 2));
    bf* W1b = (bf*)(base + take2((size_t)P_DIM * D_DIM * 2));
    bf* W2b = (bf*)(base + take2((size_t)P_DIM * P_DIM * 2));
    // P3 view
    bf* Sb    = (bf*)(base + Dbase);
    bf* Opart = (bf*)(base + Dbase + (size_t)B_ROWS * NBANK * 2);
    // P4 view
    float* G     = (float*)(base + Dbase);
    float* Fsum  = (float*)(base + Dbase + (size_t)2 * B_ROWS * D_DIM * 4);
    bf*    Fsumb = (bf*)(base + Dbase + (size_t)3 * B_ROWS * D_DIM * 4);

    auto gemm = [&](const bf* A, const bf* B, int M, int N, int K, int ldb,
                    int kch, int fx, int fy, int epi, float* Cf, bf* Cb,
                    const float* bias, const float* biasm,
                    const float* bg, const float* bb, const float* bm, const float* bv,
                    const float* addsrc, const float* lsp, int ldc) {
        gemm_bf16<<<dim3(N / 128, M / 128, kch), dim3(256), 0, stream>>>(
            A, B, M, N, K, ldb, kch, fx, fy, epi, Cf, Cb, bias, biasm,
            bg, bb, bm, bv, addsrc, lsp, ldc);
    };

    // P1: conversions
    convX<<<dim3(MTOT * D_DIM / 2048), dim3(256), 0, stream>>>(Fv, Fvs, Fvt, Xb);
    convW<<<dim3(584), dim3(256), 0, stream>>>(W1, W2, Wp, W1b, W2b, Wpb);
    convW3<<<dim3(64), dim3(256), 0, stream>>>(W3, b3, W3q, W3k, W3v, b3q, b3k, b3v);
    ftpad<<<dim3(D_DIM * D_DIM / 256), dim3(256), 0, stream>>>(Ft, Ftb);

    // P2: batched pre_project, then clean q/k/vT GEMMs (no scatter)
    gemm(Xb, W1b, MTOT, P_DIM, D_DIM, D_DIM, 1, 1, 8, 1, nullptr, h1b,
         b1, nullptr, g1, be1, m1, v1, nullptr, nullptr, 0);
    gemm(h1b, W2b, MTOT, P_DIM, P_DIM, P_DIM, 1, 1, 8, 1, nullptr, h2b,
         b2, nullptr, g2, be2, m2, v2, nullptr, nullptr, 0);
    gemm(h2b, W3q, B_ROWS, D_DIM, P_DIM, P_DIM, 1, 1, 8, 5, nullptr, qb,
         b3q, nullptr, nullptr, nullptr, nullptr, nullptr, nullptr, nullptr, 0);
    gemm(h2b + (size_t)B_ROWS * P_DIM, W3k, 2 * NBANK, D_DIM, P_DIM, P_DIM, 1,
         1, 8, 5, nullptr, kall, b3k, nullptr, nullptr, nullptr, nullptr, nullptr,
         nullptr, nullptr, 0);
    gemm(W3v, h2b + (size_t)B_ROWS * P_DIM, D_DIM, 2 * NBANK, P_DIM, P_DIM, 1,
         8, 1, 5, nullptr, vTall, nullptr, b3v, nullptr, nullptr, nullptr, nullptr,
         nullptr, nullptr, 0);

    // P3: per side: QK^T (exp fused) -> rowsum -> split-K A@V -> reduce+scale
    for (int side = 0; side < 2; ++side) {
        const bf* kb = kall + (size_t)side * NBANK * D_DIM;
        const bf* vT = vTall + (size_t)side * NBANK;
        bf* Yb = side ? Ytb : Ysb;
        gemm(qb, kb, B_ROWS, NBANK, D_DIM, D_DIM, 1, 4, 2, 7, nullptr, Sb,
             nullptr, nullptr, nullptr, nullptr, nullptr, nullptr,
             nullptr, nullptr, 0);
        rowsum_k<<<dim3(B_ROWS), dim3(256), 0, stream>>>(Sb, rsum);
        gemm(Sb, vT, B_ROWS, D_DIM, NBANK, 2 * NBANK, KSPLIT, 1, 8, 6,
             nullptr, Opart, nullptr, nullptr, nullptr, nullptr, nullptr, nullptr,
             nullptr, nullptr, 0);
        reduce_parts<<<dim3(B_ROWS * D_DIM / 2048), dim3(256), 0, stream>>>(
            Opart, (size_t)B_ROWS * D_DIM, rsum, Yb, B_ROWS * D_DIM);
    }

    // P4: combined post-project (M=8192) + dual rownorm + logits
    gemm(Yst, Wpb, 2 * B_ROWS, D_DIM, D_DIM, D_DIM, 1, 1, 8, 3, G, nullptr,
         bp, nullptr, nullptr, nullptr, nullptr, nullptr, Fv, nullptr, B_ROWS);
    rownorm2<<<dim3(B_ROWS), dim3(256), 0, stream>>>(G, Fsum);
    f2b<<<dim3(B_ROWS * D_DIM / 2048), dim3(256), 0, stream>>>(
        Fsum, Fsumb, B_ROWS * D_DIM);
    gemm(Fsumb, Ftb, B_ROWS, D_DIM, D_DIM, D_DIM, 1, 1, 8, 4, (float*)d_out, nullptr,
         nullptr, nullptr, nullptr, nullptr, nullptr, nullptr, nullptr, ls, C_CLS);
}